// Round 2
// baseline (1224.741 us; speedup 1.0000x reference)
//
#include <hip/hip_runtime.h>
#include <math.h>

#define B_ 8
#define N_ 20000
#define K_ 128
#define C_ 256

static_assert(N_ % 32 == 0, "N must be multiple of 32");

constexpr float LMBDA = 100.0f;
constexpr float EPS_EV = 1e-10f;

typedef unsigned int u32x4 __attribute__((ext_vector_type(4)));
typedef short short8_t __attribute__((ext_vector_type(8)));
typedef float f32x4 __attribute__((ext_vector_type(4)));

// split fp32 x into bf16 hi (low 16 bits) and bf16 lo (high 16 bits), RNE both.
static __device__ inline unsigned int split_bf(float x) {
  unsigned u = __builtin_bit_cast(unsigned, x);
  unsigned hi = (u + 0x7FFFu + ((u >> 16) & 1u)) >> 16;
  float hv = __builtin_bit_cast(float, hi << 16);
  float r = x - hv;  // exact
  unsigned v = __builtin_bit_cast(unsigned, r);
  unsigned lo = (v + 0x7FFFu + ((v >> 16) & 1u)) >> 16;
  return hi | (lo << 16);
}

// pack low 16-bit halves of 8 u32 -> 8 bf16 (hi plane)
static __device__ inline u32x4 pack_lo(u32x4 a, u32x4 b) {
  u32x4 r;
  r.x = __builtin_amdgcn_perm(a.y, a.x, 0x05040100u);
  r.y = __builtin_amdgcn_perm(a.w, a.z, 0x05040100u);
  r.z = __builtin_amdgcn_perm(b.y, b.x, 0x05040100u);
  r.w = __builtin_amdgcn_perm(b.w, b.z, 0x05040100u);
  return r;
}
static __device__ inline u32x4 pack_hi(u32x4 a, u32x4 b) {
  u32x4 r;
  r.x = __builtin_amdgcn_perm(a.y, a.x, 0x07060302u);
  r.y = __builtin_amdgcn_perm(a.w, a.z, 0x07060302u);
  r.z = __builtin_amdgcn_perm(b.y, b.x, 0x07060302u);
  r.w = __builtin_amdgcn_perm(b.w, b.z, 0x07060302u);
  return r;
}

#define MFMA(a, b, c) __builtin_amdgcn_mfma_f32_16x16x32_bf16( \
    __builtin_bit_cast(short8_t, a), __builtin_bit_cast(short8_t, b), c, 0, 0, 0)

// ---------------------------------------------------------------------------
// Kernel 1: projection GEMM via bf16x3-split MFMA.
// out[m=krow, c] = sum_n E[m][n] * F[n][c].
// Block: 512 thr (8 waves as 4m x 2c), tile BM=128 x BN=128, BK(n)=32.
// LDS holds (hi|lo<<16) u32 per element; A k-contig [m][k], B transposed
// [c][k] with XOR swizzle on k to kill transpose-write bank conflicts.
// Split over n into Sa chunks -> fp32 partials.
// ---------------------------------------------------------------------------
__global__ __launch_bounds__(512)
void proj_mfma(const float* __restrict__ feat_x, const float* __restrict__ feat_y,
               const float* __restrict__ evx, const float* __restrict__ evy,
               float* __restrict__ part, int Sa, int chunk) {
  const int bm = blockIdx.z;
  const int b = bm >> 1, mat = bm & 1;
  const float* __restrict__ E = (mat ? evy : evx) + (size_t)b * K_ * N_;
  const float* __restrict__ F = (mat ? feat_y : feat_x) + (size_t)b * N_ * C_;
  const int c0 = blockIdx.x << 7;
  const int s = blockIdx.y;
  const int nb = s * chunk;
  const int ne = min(N_, nb + chunk);
  const int nt = (ne - nb) >> 5;

  __shared__ unsigned int As[128][36];  // [m][k] hi|lo
  __shared__ unsigned int Bs[128][36];  // [c][k^sw]

  const int t = threadIdx.x;
  const int lane = t & 63, wv = t >> 6;
  const int wm = wv & 3, wc = wv >> 1 & ~0;  // wm 0..3
  const int wcc = wv >> 2;                   // wc 0..1
  const int lr = lane & 15, lg = lane >> 4;
  const int k0 = lg << 3;

  f32x4 acc[2][4];
#pragma unroll
  for (int i = 0; i < 2; ++i)
#pragma unroll
    for (int j = 0; j < 4; ++j) acc[i][j] = (f32x4){0.f, 0.f, 0.f, 0.f};

  // staging register double-buffer
  float4 ea[2], fb[2];
  {
    const int n0 = nb;
#pragma unroll
    for (int l2 = 0; l2 < 2; ++l2) {
      int f = t + (l2 << 9);
      int m = f >> 3, kq = (f & 7) << 2;
      ea[l2] = *(const float4*)(E + (size_t)m * N_ + (n0 + kq));
      int nn = f >> 5, cq = (f & 31) << 2;
      fb[l2] = *(const float4*)(F + (size_t)(n0 + nn) * C_ + (c0 + cq));
    }
  }

  for (int it = 0; it < nt; ++it) {
    __syncthreads();  // LDS free (prev compute done)
    // convert + write staged regs to LDS
#pragma unroll
    for (int l2 = 0; l2 < 2; ++l2) {
      int f = t + (l2 << 9);
      int m = f >> 3, kq = (f & 7) << 2;
      u32x4 w;
      w.x = split_bf(ea[l2].x); w.y = split_bf(ea[l2].y);
      w.z = split_bf(ea[l2].z); w.w = split_bf(ea[l2].w);
      *(u32x4*)&As[m][kq] = w;
      int nn = f >> 5, cq = (f & 31) << 2;
      int sw = ((cq >> 3) & 7) << 2;
      int col = nn ^ sw;
      Bs[cq + 0][col] = split_bf(fb[l2].x);
      Bs[cq + 1][col] = split_bf(fb[l2].y);
      Bs[cq + 2][col] = split_bf(fb[l2].z);
      Bs[cq + 3][col] = split_bf(fb[l2].w);
    }
    // prefetch next tile into regs (overlaps with compute below)
    if (it + 1 < nt) {
      const int n0 = nb + ((it + 1) << 5);
#pragma unroll
      for (int l2 = 0; l2 < 2; ++l2) {
        int f = t + (l2 << 9);
        int m = f >> 3, kq = (f & 7) << 2;
        ea[l2] = *(const float4*)(E + (size_t)m * N_ + (n0 + kq));
        int nn = f >> 5, cq = (f & 31) << 2;
        fb[l2] = *(const float4*)(F + (size_t)(n0 + nn) * C_ + (c0 + cq));
      }
    }
    __syncthreads();  // LDS ready

    u32x4 bh[4], bl4[4];
#pragma unroll
    for (int ct = 0; ct < 4; ++ct) {
      const int c = (wcc << 6) + (ct << 4) + lr;
      const int sw = ((c >> 3) & 7) << 2;
      u32x4 q0 = *(const u32x4*)&Bs[c][k0 ^ sw];
      u32x4 q1 = *(const u32x4*)&Bs[c][(k0 + 4) ^ sw];
      bh[ct] = pack_lo(q0, q1);
      bl4[ct] = pack_hi(q0, q1);
    }
#pragma unroll
    for (int mt = 0; mt < 2; ++mt) {
      const int m = (wm << 5) + (mt << 4) + lr;
      u32x4 q0 = *(const u32x4*)&As[m][k0];
      u32x4 q1 = *(const u32x4*)&As[m][k0 + 4];
      u32x4 ah = pack_lo(q0, q1);
      u32x4 al = pack_hi(q0, q1);
#pragma unroll
      for (int ct = 0; ct < 4; ++ct) {
        acc[mt][ct] = MFMA(ah, bh[ct], acc[mt][ct]);
        acc[mt][ct] = MFMA(al, bh[ct], acc[mt][ct]);
        acc[mt][ct] = MFMA(ah, bl4[ct], acc[mt][ct]);
      }
    }
  }

  // epilogue: C/D layout col=lane&15, row=(lane>>4)*4+r
  float* __restrict__ P = part + ((size_t)bm * Sa + s) * (K_ * C_);
#pragma unroll
  for (int mt = 0; mt < 2; ++mt)
#pragma unroll
    for (int ct = 0; ct < 4; ++ct) {
      const int ccol = c0 + (wcc << 6) + (ct << 4) + lr;
#pragma unroll
      for (int r = 0; r < 4; ++r) {
        const int mrow = (wm << 5) + (mt << 4) + (lg << 2) + r;
        P[(size_t)mrow * C_ + ccol] = acc[mt][ct][r];
      }
    }
}

// ---------------------------------------------------------------------------
// Kernel 2: reduce split-n partials -> AB
// ---------------------------------------------------------------------------
__global__ void reduce_parts(const float* __restrict__ part, float* __restrict__ AB, int Sa) {
  int idx = blockIdx.x * 256 + threadIdx.x;
  if (idx >= 16 * K_ * C_) return;
  int bm = idx / (K_ * C_);
  int rem = idx - bm * (K_ * C_);
  float v = 0.f;
  for (int s = 0; s < Sa; ++s) v += part[((size_t)bm * Sa + s) * (K_ * C_) + rem];
  AB[idx] = v;
}

// ---------------------------------------------------------------------------
// Kernel 3: gram matrices.  which=0: Sm = A A^T + 1e-8 I ; which=1: Rm = Bm A^T
// ---------------------------------------------------------------------------
__global__ __launch_bounds__(256)
void gram_kernel(const float* __restrict__ AB, float* __restrict__ Sm, float* __restrict__ Rm) {
  const int b = blockIdx.x, which = blockIdx.y;
  const float* __restrict__ L  = AB + ((size_t)(b * 2 + which)) * (K_ * C_);
  const float* __restrict__ Ar = AB + ((size_t)(b * 2)) * (K_ * C_);
  float* __restrict__ out = (which ? Rm : Sm) + (size_t)b * (K_ * K_);
  const int t = threadIdx.x;
  const int ir = (t >> 4) << 3, jc = (t & 15) << 3;
  float acc[8][8] = {};
  for (int c0 = 0; c0 < C_; c0 += 4) {
    float4 li[8], rj[8];
#pragma unroll
    for (int i = 0; i < 8; ++i) li[i] = *(const float4*)(L + (size_t)(ir + i) * C_ + c0);
#pragma unroll
    for (int j = 0; j < 8; ++j) rj[j] = *(const float4*)(Ar + (size_t)(jc + j) * C_ + c0);
#pragma unroll
    for (int i = 0; i < 8; ++i)
#pragma unroll
      for (int j = 0; j < 8; ++j)
        acc[i][j] += li[i].x * rj[j].x + li[i].y * rj[j].y +
                     li[i].z * rj[j].z + li[i].w * rj[j].w;
  }
#pragma unroll
  for (int i = 0; i < 8; ++i)
#pragma unroll
    for (int j = 0; j < 8; ++j) {
      float v = acc[i][j];
      if (!which && (ir + i) == (jc + j)) v += 1e-8f;
      out[(size_t)(ir + i) * K_ + (jc + j)] = v;
    }
}

// ---------------------------------------------------------------------------
// Kernel 4: mask prep -> q1,p1 (cols, evals_x), q2,p2 (rows, evals_y)
// ---------------------------------------------------------------------------
__global__ void mask_prep(const float* __restrict__ evx, const float* __restrict__ evy,
                          float* __restrict__ PQ) {
  const int b = blockIdx.x, t = threadIdx.x;  // 128 threads
  float e1 = evx[b * K_ + t];
  float e2 = evy[b * K_ + t];
  if (e1 != e1) e1 = EPS_EV;
  if (e2 != e2) e2 = EPS_EV;
  e1 = fminf(fmaxf(e1, EPS_EV), 1e6f);
  e2 = fminf(fmaxf(e2, EPS_EV), 1e6f);

  __shared__ float wmax[2];
  float v = fmaxf(e1, e2);
#pragma unroll
  for (int d = 1; d < 64; d <<= 1) v = fmaxf(v, __shfl_xor(v, d, 64));
  if ((t & 63) == 0) wmax[t >> 6] = v;
  __syncthreads();
  const float scale = fmaxf(fmaxf(wmax[0], wmax[1]), 1e-10f);

  const float g1 = sqrtf(e1 / scale);
  const float g2 = sqrtf(e2 / scale);
  const float d1 = fmaf(g1, g1, 1.f);
  const float d2 = fmaf(g2, g2, 1.f);
  float* P = PQ + b * 512;
  P[t]       = g1 / d1;
  P[128 + t] = 1.f / d1;
  P[256 + t] = g2 / d2;
  P[384 + t] = 1.f / d2;
}

// ---------------------------------------------------------------------------
// Kernel 5: Gauss-Jordan inverse (SPD, no pivoting), 1024 threads.
// Each thread owns 4 float4 cells (rows t>>5 + 32l, cols (t&31)*4..+3).
// Pivot row/col read directly (same-address LDS reads broadcast free).
// ---------------------------------------------------------------------------
__global__ __launch_bounds__(1024)
void gj_inverse(const float* __restrict__ Sm, float* __restrict__ Sinv) {
  const int b = blockIdx.x, t = threadIdx.x;
  __shared__ float a[K_ * 132];
  const float* __restrict__ Sb = Sm + (size_t)b * (K_ * K_);
#pragma unroll
  for (int l = 0; l < 4; ++l) {
    int f = t + (l << 10);
    int i = f >> 5, j = (f & 31) << 2;
    *(float4*)&a[i * 132 + j] = *(const float4*)(Sb + i * K_ + j);
  }
  __syncthreads();
  const int j4 = (t & 31) << 2;
  const int r0 = t >> 5;
  for (int k = 0; k < K_; ++k) {
    // read phase: pivot row segment, pivot, pivot-col entries for owned rows
    float4 rp = *(const float4*)&a[k * 132 + j4];
    const float piv = a[k * 132 + k];
    float ci[4];
#pragma unroll
    for (int l = 0; l < 4; ++l) ci[l] = a[(r0 + (l << 5)) * 132 + k];
    const float p = 1.0f / piv;
    rp.x *= p; rp.y *= p; rp.z *= p; rp.w *= p;
    const bool jhit = (k >= j4) && (k < j4 + 4);
    __syncthreads();  // everyone done reading old values
#pragma unroll
    for (int l = 0; l < 4; ++l) {
      const int i = r0 + (l << 5);
      float4 v = *(float4*)&a[i * 132 + j4];
      if (i == k) {
        v = rp;
        if (jhit) ((float*)&v)[k - j4] = p;
      } else {
        const float c = ci[l];
        v.x = fmaf(-c, rp.x, v.x);
        v.y = fmaf(-c, rp.y, v.y);
        v.z = fmaf(-c, rp.z, v.z);
        v.w = fmaf(-c, rp.w, v.w);
        if (jhit) ((float*)&v)[k - j4] = -c * p;
      }
      *(float4*)&a[i * 132 + j4] = v;
    }
    __syncthreads();
  }
  float* __restrict__ O = Sinv + (size_t)b * (K_ * K_);
#pragma unroll
  for (int l = 0; l < 4; ++l) {
    int f = t + (l << 10);
    int i = f >> 5, j = (f & 31) << 2;
    *(float4*)(O + i * K_ + j) = *(const float4*)&a[i * 132 + j];
  }
}

// ---------------------------------------------------------------------------
// Kernel 6: Neumann iteration.  Xout = (R - W .* Xin) @ Sinv
// W[i,k] = LMBDA * ((q2[i]-q1[k])^2 + (p2[i]-p1[k])^2).  first=1 -> T = R.
// ---------------------------------------------------------------------------
__global__ __launch_bounds__(256)
void solve_iter(const float* __restrict__ Rm, const float* __restrict__ Sinv,
                const float* __restrict__ PQ, const float* __restrict__ Xin,
                float* __restrict__ Xout, const int first) {
  const int b = blockIdx.x, t = threadIdx.x;
  __shared__ float Tt[32][128];
  __shared__ float Sv[32][128];
  __shared__ float q1[K_], p1[K_], q2[K_], p2[K_];
  if (t < K_) {
    const float* P = PQ + b * 512;
    q1[t] = P[t]; p1[t] = P[128 + t]; q2[t] = P[256 + t]; p2[t] = P[384 + t];
  }
  __syncthreads();
  const float* __restrict__ Rb = Rm + (size_t)b * (K_ * K_);
  const float* __restrict__ Xb = Xin + (size_t)b * (K_ * K_);
  const float* __restrict__ Si = Sinv + (size_t)b * (K_ * K_);
  const int ir = (t >> 4) << 3, jc = (t & 15) << 3;
  float acc[8][8] = {};

  for (int k0 = 0; k0 < K_; k0 += 32) {
#pragma unroll
    for (int l = 0; l < 4; ++l) {
      int f = t + (l << 8);
      int i = f >> 3;
      int kk = (f & 7) << 2;
      const int k = k0 + kk;
      float4 tv = *(const float4*)(Rb + (size_t)i * K_ + k);
      if (!first) {
        const float4 x4 = *(const float4*)(Xb + (size_t)i * K_ + k);
        const float qi = q2[i], pi = p2[i];
        float dq, dp, w;
        dq = qi - q1[k + 0]; dp = pi - p1[k + 0]; w = fmaf(dq, dq, dp * dp);
        tv.x = fmaf(-LMBDA * w, x4.x, tv.x);
        dq = qi - q1[k + 1]; dp = pi - p1[k + 1]; w = fmaf(dq, dq, dp * dp);
        tv.y = fmaf(-LMBDA * w, x4.y, tv.y);
        dq = qi - q1[k + 2]; dp = pi - p1[k + 2]; w = fmaf(dq, dq, dp * dp);
        tv.z = fmaf(-LMBDA * w, x4.z, tv.z);
        dq = qi - q1[k + 3]; dp = pi - p1[k + 3]; w = fmaf(dq, dq, dp * dp);
        tv.w = fmaf(-LMBDA * w, x4.w, tv.w);
      }
      Tt[kk + 0][i] = tv.x; Tt[kk + 1][i] = tv.y;
      Tt[kk + 2][i] = tv.z; Tt[kk + 3][i] = tv.w;
    }
#pragma unroll
    for (int l = 0; l < 4; ++l) {
      int f = t + (l << 8);
      int kk = f >> 5, j = (f & 31) << 2;
      *(float4*)&Sv[kk][j] = *(const float4*)(Si + (size_t)(k0 + kk) * K_ + j);
    }
    __syncthreads();
#pragma unroll
    for (int kk = 0; kk < 32; ++kk) {
      const float4 a0 = *(const float4*)&Tt[kk][ir];
      const float4 a1 = *(const float4*)&Tt[kk][ir + 4];
      const float4 b0 = *(const float4*)&Sv[kk][jc];
      const float4 b1 = *(const float4*)&Sv[kk][jc + 4];
      const float av[8] = {a0.x, a0.y, a0.z, a0.w, a1.x, a1.y, a1.z, a1.w};
      const float bv[8] = {b0.x, b0.y, b0.z, b0.w, b1.x, b1.y, b1.z, b1.w};
#pragma unroll
      for (int i = 0; i < 8; ++i)
#pragma unroll
        for (int j = 0; j < 8; ++j)
          acc[i][j] = fmaf(av[i], bv[j], acc[i][j]);
    }
    __syncthreads();
  }

  float* __restrict__ O = Xout + (size_t)b * (K_ * K_);
#pragma unroll
  for (int i = 0; i < 8; ++i) {
    float4 o0 = {acc[i][0], acc[i][1], acc[i][2], acc[i][3]};
    float4 o1 = {acc[i][4], acc[i][5], acc[i][6], acc[i][7]};
    *(float4*)(O + (size_t)(ir + i) * K_ + jc) = o0;
    *(float4*)(O + (size_t)(ir + i) * K_ + jc + 4) = o1;
  }
}

// ---------------------------------------------------------------------------
extern "C" void kernel_launch(void* const* d_in, const int* in_sizes, int n_in,
                              void* d_out, int out_size, void* d_ws, size_t ws_size,
                              hipStream_t stream) {
  (void)in_sizes; (void)n_in; (void)out_size;
  const float* feat_x  = (const float*)d_in[0];
  const float* feat_y  = (const float*)d_in[1];
  const float* evals_x = (const float*)d_in[2];
  const float* evals_y = (const float*)d_in[3];
  const float* evtx    = (const float*)d_in[4];
  const float* evty    = (const float*)d_in[5];
  float* out = (float*)d_out;
  float* ws  = (float*)d_ws;

  const size_t KC16 = (size_t)16 * K_ * C_;  // 524288 floats (AB / one slab)
  const size_t KK   = (size_t)K_ * K_;       // 16384
  const size_t fixed = KC16 + 3 * (KK * B_) + 4096 + 2 * (KK * B_);
  const int T = N_ / 32;  // 625 k-steps total

  int S = 16, Sa = 16, chunk = 0;
  for (;;) {
    int steps = (T + S - 1) / S;
    chunk = steps * 32;
    Sa = (T + steps - 1) / steps;  // active slabs, all with nb < N_
    if (((size_t)Sa * KC16 + fixed) * sizeof(float) <= ws_size || S == 1) break;
    S >>= 1;
  }

  float* part = ws;
  float* AB   = part + (size_t)Sa * KC16;
  float* Sm   = AB + KC16;
  float* Rm   = Sm + KK * B_;
  float* Sinv = Rm + KK * B_;
  float* PQ   = Sinv + KK * B_;
  float* X0   = PQ + 4096;
  float* X1   = X0 + KK * B_;

  proj_mfma<<<dim3(2, Sa, 16), 512, 0, stream>>>(feat_x, feat_y, evtx, evty, part, Sa, chunk);
  reduce_parts<<<dim3((16 * K_ * C_ + 255) / 256), 256, 0, stream>>>(part, AB, Sa);
  gram_kernel<<<dim3(8, 2), 256, 0, stream>>>(AB, Sm, Rm);
  mask_prep<<<dim3(8), 128, 0, stream>>>(evals_x, evals_y, PQ);
  gj_inverse<<<dim3(8), 1024, 0, stream>>>(Sm, Sinv);
  solve_iter<<<dim3(8), 256, 0, stream>>>(Rm, Sinv, PQ, X0, X0, 1);
  solve_iter<<<dim3(8), 256, 0, stream>>>(Rm, Sinv, PQ, X0, X1, 0);
  solve_iter<<<dim3(8), 256, 0, stream>>>(Rm, Sinv, PQ, X1, out, 0);
}

// Round 3
// 350.662 us; speedup vs baseline: 3.4927x; 3.4927x over previous
//
#include <hip/hip_runtime.h>
#include <math.h>

#define B_ 8
#define N_ 20000
#define K_ 128
#define C_ 256

static_assert(N_ % 32 == 0, "N must be multiple of 32");

constexpr float LMBDA = 100.0f;
constexpr float EPS_EV = 1e-10f;

typedef unsigned int u32x4 __attribute__((ext_vector_type(4)));
typedef short short8_t __attribute__((ext_vector_type(8)));
typedef float f32x4 __attribute__((ext_vector_type(4)));

// split fp32 x into bf16 hi (low 16 bits) and bf16 lo (high 16 bits), RNE both.
static __device__ inline unsigned int split_bf(float x) {
  unsigned u = __builtin_bit_cast(unsigned, x);
  unsigned hi = (u + 0x7FFFu + ((u >> 16) & 1u)) >> 16;
  float hv = __builtin_bit_cast(float, hi << 16);
  float r = x - hv;  // exact
  unsigned v = __builtin_bit_cast(unsigned, r);
  unsigned lo = (v + 0x7FFFu + ((v >> 16) & 1u)) >> 16;
  return hi | (lo << 16);
}

// pack low 16-bit halves of 8 u32 -> 8 bf16 (hi plane)
static __device__ inline u32x4 pack_lo(u32x4 a, u32x4 b) {
  u32x4 r;
  r.x = __builtin_amdgcn_perm(a.y, a.x, 0x05040100u);
  r.y = __builtin_amdgcn_perm(a.w, a.z, 0x05040100u);
  r.z = __builtin_amdgcn_perm(b.y, b.x, 0x05040100u);
  r.w = __builtin_amdgcn_perm(b.w, b.z, 0x05040100u);
  return r;
}
static __device__ inline u32x4 pack_hi(u32x4 a, u32x4 b) {
  u32x4 r;
  r.x = __builtin_amdgcn_perm(a.y, a.x, 0x07060302u);
  r.y = __builtin_amdgcn_perm(a.w, a.z, 0x07060302u);
  r.z = __builtin_amdgcn_perm(b.y, b.x, 0x07060302u);
  r.w = __builtin_amdgcn_perm(b.w, b.z, 0x07060302u);
  return r;
}

#define MFMA(a, b, c) __builtin_amdgcn_mfma_f32_16x16x32_bf16( \
    __builtin_bit_cast(short8_t, a), __builtin_bit_cast(short8_t, b), c, 0, 0, 0)

// ---------------------------------------------------------------------------
// Kernel 1: projection GEMM via bf16x3-split MFMA. (unchanged from round 2)
// ---------------------------------------------------------------------------
__global__ __launch_bounds__(512)
void proj_mfma(const float* __restrict__ feat_x, const float* __restrict__ feat_y,
               const float* __restrict__ evx, const float* __restrict__ evy,
               float* __restrict__ part, int Sa, int chunk) {
  const int bm = blockIdx.z;
  const int b = bm >> 1, mat = bm & 1;
  const float* __restrict__ E = (mat ? evy : evx) + (size_t)b * K_ * N_;
  const float* __restrict__ F = (mat ? feat_y : feat_x) + (size_t)b * N_ * C_;
  const int c0 = blockIdx.x << 7;
  const int s = blockIdx.y;
  const int nb = s * chunk;
  const int ne = min(N_, nb + chunk);
  const int nt = (ne - nb) >> 5;

  __shared__ unsigned int As[128][36];  // [m][k] hi|lo
  __shared__ unsigned int Bs[128][36];  // [c][k^sw]

  const int t = threadIdx.x;
  const int lane = t & 63, wv = t >> 6;
  const int wm = wv & 3;
  const int wcc = wv >> 2;
  const int lr = lane & 15, lg = lane >> 4;
  const int k0 = lg << 3;

  f32x4 acc[2][4];
#pragma unroll
  for (int i = 0; i < 2; ++i)
#pragma unroll
    for (int j = 0; j < 4; ++j) acc[i][j] = (f32x4){0.f, 0.f, 0.f, 0.f};

  float4 ea[2], fb[2];
  {
    const int n0 = nb;
#pragma unroll
    for (int l2 = 0; l2 < 2; ++l2) {
      int f = t + (l2 << 9);
      int m = f >> 3, kq = (f & 7) << 2;
      ea[l2] = *(const float4*)(E + (size_t)m * N_ + (n0 + kq));
      int nn = f >> 5, cq = (f & 31) << 2;
      fb[l2] = *(const float4*)(F + (size_t)(n0 + nn) * C_ + (c0 + cq));
    }
  }

  for (int it = 0; it < nt; ++it) {
    __syncthreads();
#pragma unroll
    for (int l2 = 0; l2 < 2; ++l2) {
      int f = t + (l2 << 9);
      int m = f >> 3, kq = (f & 7) << 2;
      u32x4 w;
      w.x = split_bf(ea[l2].x); w.y = split_bf(ea[l2].y);
      w.z = split_bf(ea[l2].z); w.w = split_bf(ea[l2].w);
      *(u32x4*)&As[m][kq] = w;
      int nn = f >> 5, cq = (f & 31) << 2;
      int sw = ((cq >> 3) & 7) << 2;
      int col = nn ^ sw;
      Bs[cq + 0][col] = split_bf(fb[l2].x);
      Bs[cq + 1][col] = split_bf(fb[l2].y);
      Bs[cq + 2][col] = split_bf(fb[l2].z);
      Bs[cq + 3][col] = split_bf(fb[l2].w);
    }
    if (it + 1 < nt) {
      const int n0 = nb + ((it + 1) << 5);
#pragma unroll
      for (int l2 = 0; l2 < 2; ++l2) {
        int f = t + (l2 << 9);
        int m = f >> 3, kq = (f & 7) << 2;
        ea[l2] = *(const float4*)(E + (size_t)m * N_ + (n0 + kq));
        int nn = f >> 5, cq = (f & 31) << 2;
        fb[l2] = *(const float4*)(F + (size_t)(n0 + nn) * C_ + (c0 + cq));
      }
    }
    __syncthreads();

    u32x4 bh[4], bl4[4];
#pragma unroll
    for (int ct = 0; ct < 4; ++ct) {
      const int c = (wcc << 6) + (ct << 4) + lr;
      const int sw = ((c >> 3) & 7) << 2;
      u32x4 q0 = *(const u32x4*)&Bs[c][k0 ^ sw];
      u32x4 q1 = *(const u32x4*)&Bs[c][(k0 + 4) ^ sw];
      bh[ct] = pack_lo(q0, q1);
      bl4[ct] = pack_hi(q0, q1);
    }
#pragma unroll
    for (int mt = 0; mt < 2; ++mt) {
      const int m = (wm << 5) + (mt << 4) + lr;
      u32x4 q0 = *(const u32x4*)&As[m][k0];
      u32x4 q1 = *(const u32x4*)&As[m][k0 + 4];
      u32x4 ah = pack_lo(q0, q1);
      u32x4 al = pack_hi(q0, q1);
#pragma unroll
      for (int ct = 0; ct < 4; ++ct) {
        acc[mt][ct] = MFMA(ah, bh[ct], acc[mt][ct]);
        acc[mt][ct] = MFMA(al, bh[ct], acc[mt][ct]);
        acc[mt][ct] = MFMA(ah, bl4[ct], acc[mt][ct]);
      }
    }
  }

  float* __restrict__ P = part + ((size_t)bm * Sa + s) * (K_ * C_);
#pragma unroll
  for (int mt = 0; mt < 2; ++mt)
#pragma unroll
    for (int ct = 0; ct < 4; ++ct) {
      const int ccol = c0 + (wcc << 6) + (ct << 4) + lr;
#pragma unroll
      for (int r = 0; r < 4; ++r) {
        const int mrow = (wm << 5) + (mt << 4) + (lg << 2) + r;
        P[(size_t)mrow * C_ + ccol] = acc[mt][ct][r];
      }
    }
}

// ---------------------------------------------------------------------------
// Kernel 2: reduce split-n partials -> AB (unchanged)
// ---------------------------------------------------------------------------
__global__ void reduce_parts(const float* __restrict__ part, float* __restrict__ AB, int Sa) {
  int idx = blockIdx.x * 256 + threadIdx.x;
  if (idx >= 16 * K_ * C_) return;
  int bm = idx / (K_ * C_);
  int rem = idx - bm * (K_ * C_);
  float v = 0.f;
  for (int s = 0; s < Sa; ++s) v += part[((size_t)bm * Sa + s) * (K_ * C_) + rem];
  AB[idx] = v;
}

// ---------------------------------------------------------------------------
// Kernel 3: gram matrices (unchanged)
// ---------------------------------------------------------------------------
__global__ __launch_bounds__(256)
void gram_kernel(const float* __restrict__ AB, float* __restrict__ Sm, float* __restrict__ Rm) {
  const int b = blockIdx.x, which = blockIdx.y;
  const float* __restrict__ L  = AB + ((size_t)(b * 2 + which)) * (K_ * C_);
  const float* __restrict__ Ar = AB + ((size_t)(b * 2)) * (K_ * C_);
  float* __restrict__ out = (which ? Rm : Sm) + (size_t)b * (K_ * K_);
  const int t = threadIdx.x;
  const int ir = (t >> 4) << 3, jc = (t & 15) << 3;
  float acc[8][8] = {};
  for (int c0 = 0; c0 < C_; c0 += 4) {
    float4 li[8], rj[8];
#pragma unroll
    for (int i = 0; i < 8; ++i) li[i] = *(const float4*)(L + (size_t)(ir + i) * C_ + c0);
#pragma unroll
    for (int j = 0; j < 8; ++j) rj[j] = *(const float4*)(Ar + (size_t)(jc + j) * C_ + c0);
#pragma unroll
    for (int i = 0; i < 8; ++i)
#pragma unroll
      for (int j = 0; j < 8; ++j)
        acc[i][j] += li[i].x * rj[j].x + li[i].y * rj[j].y +
                     li[i].z * rj[j].z + li[i].w * rj[j].w;
  }
#pragma unroll
  for (int i = 0; i < 8; ++i)
#pragma unroll
    for (int j = 0; j < 8; ++j) {
      float v = acc[i][j];
      if (!which && (ir + i) == (jc + j)) v += 1e-8f;
      out[(size_t)(ir + i) * K_ + (jc + j)] = v;
    }
}

// ---------------------------------------------------------------------------
// Kernel 4: mask prep (unchanged)
// ---------------------------------------------------------------------------
__global__ void mask_prep(const float* __restrict__ evx, const float* __restrict__ evy,
                          float* __restrict__ PQ) {
  const int b = blockIdx.x, t = threadIdx.x;  // 128 threads
  float e1 = evx[b * K_ + t];
  float e2 = evy[b * K_ + t];
  if (e1 != e1) e1 = EPS_EV;
  if (e2 != e2) e2 = EPS_EV;
  e1 = fminf(fmaxf(e1, EPS_EV), 1e6f);
  e2 = fminf(fmaxf(e2, EPS_EV), 1e6f);

  __shared__ float wmax[2];
  float v = fmaxf(e1, e2);
#pragma unroll
  for (int d = 1; d < 64; d <<= 1) v = fmaxf(v, __shfl_xor(v, d, 64));
  if ((t & 63) == 0) wmax[t >> 6] = v;
  __syncthreads();
  const float scale = fmaxf(fmaxf(wmax[0], wmax[1]), 1e-10f);

  const float g1 = sqrtf(e1 / scale);
  const float g2 = sqrtf(e2 / scale);
  const float d1 = fmaf(g1, g1, 1.f);
  const float d2 = fmaf(g2, g2, 1.f);
  float* P = PQ + b * 512;
  P[t]       = g1 / d1;
  P[128 + t] = 1.f / d1;
  P[256 + t] = g2 / d2;
  P[384 + t] = 1.f / d2;
}

// ---------------------------------------------------------------------------
// Kernel 5: BLOCKED Gauss-Jordan inverse (SPD, no pivoting needed).
// 8 panels of 16 columns. Per panel:
//   ph1: wave 0 inverts the 16x16 pivot block fully in registers (shuffles).
//   ph2: Rp = Pinv @ A[p,:] (p-cols := Pinv); Cp = A[:,p] saved.
//   ph3: A[i,:] -= Cp[i,:] @ Rp  (i not in p; p-cols get -Cp@Pinv; p-rows = Rp).
// 3 barriers/panel -> 24 barriers total (vs 256 scalar). 256 threads.
// ---------------------------------------------------------------------------
__global__ __launch_bounds__(256)
void gj_inverse(const float* __restrict__ Sm, float* __restrict__ Sinv) {
  const int b = blockIdx.x, t = threadIdx.x;
  __shared__ float a[K_ * 132];
  __shared__ float Pi[16 * 20];
  __shared__ float Rp[16 * 132];
  __shared__ float Cp[K_ * 20];
  const float* __restrict__ Sb = Sm + (size_t)b * (K_ * K_);
#pragma unroll
  for (int l = 0; l < 16; ++l) {
    int f = t + (l << 8);
    int i = f >> 5, j = (f & 31) << 2;
    *(float4*)&a[i * 132 + j] = *(const float4*)(Sb + i * K_ + j);
  }
  __syncthreads();

  const int j = t & 127, h = t >> 7;   // h in {0,1}
  const int lane = t & 63;

  for (int p = 0; p < 8; ++p) {
    const int pb = p << 4;

    // ---- phase 1: wave 0 inverts the 16x16 pivot block in registers ----
    if (t < 64) {
      const int r = lane & 15, g = lane >> 4;  // row r, cols 4g..4g+3
      float4 v4 = *(const float4*)&a[(pb + r) * 132 + pb + (g << 2)];
      float vv[4] = {v4.x, v4.y, v4.z, v4.w};
#pragma unroll
      for (int k = 0; k < 16; ++k) {
        const int srcrow = (lane & 48) | k;        // lane holding row k, my col group
        float rk[4];
        rk[0] = __shfl(vv[0], srcrow);
        rk[1] = __shfl(vv[1], srcrow);
        rk[2] = __shfl(vv[2], srcrow);
        rk[3] = __shfl(vv[3], srcrow);
        const int kg = (k >> 2) << 4;              // lane group holding col k
        const float pv = __shfl(vv[k & 3], kg | k);
        const float c  = __shfl(vv[k & 3], kg | r);
        const float pr = 1.0f / pv;
        float rs[4];
#pragma unroll
        for (int e = 0; e < 4; ++e) rs[e] = rk[e] * pr;
        if (r == k) {
#pragma unroll
          for (int e = 0; e < 4; ++e) vv[e] = rs[e];
          if (g == (k >> 2)) vv[k & 3] = pr;
        } else {
#pragma unroll
          for (int e = 0; e < 4; ++e) vv[e] = fmaf(-c, rs[e], vv[e]);
          if (g == (k >> 2)) vv[k & 3] = -c * pr;
        }
      }
      Pi[r * 20 + (g << 2) + 0] = vv[0];
      Pi[r * 20 + (g << 2) + 1] = vv[1];
      Pi[r * 20 + (g << 2) + 2] = vv[2];
      Pi[r * 20 + (g << 2) + 3] = vv[3];
    }
    __syncthreads();

    // ---- phase 2: Rp = Pinv @ A[p,:]  (p-cols := Pinv); save Cp = A[:,p] ----
    {
      float Ak[16];
#pragma unroll
      for (int k = 0; k < 16; ++k) Ak[k] = a[(pb + k) * 132 + j];
      const unsigned jj = (unsigned)(j - pb);
      const int r0 = h << 3;
#pragma unroll
      for (int q = 0; q < 8; ++q) {
        const int r = r0 + q;
        float acc = 0.f;
#pragma unroll
        for (int k = 0; k < 16; ++k) acc = fmaf(Pi[r * 20 + k], Ak[k], acc);
        Rp[r * 132 + j] = (jj < 16u) ? Pi[r * 20 + jj] : acc;
      }
      const int i = j;
      const int cb = h << 3;
      float4 cA = *(const float4*)&a[i * 132 + pb + cb];
      float4 cB = *(const float4*)&a[i * 132 + pb + cb + 4];
      *(float4*)&Cp[i * 20 + cb] = cA;
      *(float4*)&Cp[i * 20 + cb + 4] = cB;
    }
    __syncthreads();

    // ---- phase 3: full update ----
    {
      float Rk[16];
#pragma unroll
      for (int k = 0; k < 16; ++k) Rk[k] = Rp[k * 132 + j];
      const unsigned jj = (unsigned)(j - pb);
      const int i0 = h << 6;
#pragma unroll 4
      for (int m = 0; m < 64; ++m) {
        const int i = i0 + m;
        const float4 c0 = *(const float4*)&Cp[i * 20];
        const float4 c1 = *(const float4*)&Cp[i * 20 + 4];
        const float4 c2 = *(const float4*)&Cp[i * 20 + 8];
        const float4 c3 = *(const float4*)&Cp[i * 20 + 12];
        float u0 = c0.x * Rk[0] + c0.y * Rk[1] + c0.z * Rk[2] + c0.w * Rk[3];
        float u1 = c1.x * Rk[4] + c1.y * Rk[5] + c1.z * Rk[6] + c1.w * Rk[7];
        float u2 = c2.x * Rk[8] + c2.y * Rk[9] + c2.z * Rk[10] + c2.w * Rk[11];
        float u3 = c3.x * Rk[12] + c3.y * Rk[13] + c3.z * Rk[14] + c3.w * Rk[15];
        const float upd = (u0 + u1) + (u2 + u3);
        const unsigned ii = (unsigned)(i - pb);
        float newv;
        if (ii < 16u) {
          newv = Rk[ii];                      // p-rows: become Rp
        } else {
          const float base = (jj < 16u) ? 0.f : a[i * 132 + j];
          newv = base - upd;
        }
        a[i * 132 + j] = newv;
      }
    }
    __syncthreads();
  }

  float* __restrict__ O = Sinv + (size_t)b * (K_ * K_);
#pragma unroll
  for (int l = 0; l < 16; ++l) {
    int f = t + (l << 8);
    int i = f >> 5, jq = (f & 31) << 2;
    *(float4*)(O + i * K_ + jq) = *(const float4*)&a[i * 132 + jq];
  }
}

// ---------------------------------------------------------------------------
// Kernel 6: Neumann iteration (unchanged)
// ---------------------------------------------------------------------------
__global__ __launch_bounds__(256)
void solve_iter(const float* __restrict__ Rm, const float* __restrict__ Sinv,
                const float* __restrict__ PQ, const float* __restrict__ Xin,
                float* __restrict__ Xout, const int first) {
  const int b = blockIdx.x, t = threadIdx.x;
  __shared__ float Tt[32][128];
  __shared__ float Sv[32][128];
  __shared__ float q1[K_], p1[K_], q2[K_], p2[K_];
  if (t < K_) {
    const float* P = PQ + b * 512;
    q1[t] = P[t]; p1[t] = P[128 + t]; q2[t] = P[256 + t]; p2[t] = P[384 + t];
  }
  __syncthreads();
  const float* __restrict__ Rb = Rm + (size_t)b * (K_ * K_);
  const float* __restrict__ Xb = Xin + (size_t)b * (K_ * K_);
  const float* __restrict__ Si = Sinv + (size_t)b * (K_ * K_);
  const int ir = (t >> 4) << 3, jc = (t & 15) << 3;
  float acc[8][8] = {};

  for (int k0 = 0; k0 < K_; k0 += 32) {
#pragma unroll
    for (int l = 0; l < 4; ++l) {
      int f = t + (l << 8);
      int i = f >> 3;
      int kk = (f & 7) << 2;
      const int k = k0 + kk;
      float4 tv = *(const float4*)(Rb + (size_t)i * K_ + k);
      if (!first) {
        const float4 x4 = *(const float4*)(Xb + (size_t)i * K_ + k);
        const float qi = q2[i], pi = p2[i];
        float dq, dp, w;
        dq = qi - q1[k + 0]; dp = pi - p1[k + 0]; w = fmaf(dq, dq, dp * dp);
        tv.x = fmaf(-LMBDA * w, x4.x, tv.x);
        dq = qi - q1[k + 1]; dp = pi - p1[k + 1]; w = fmaf(dq, dq, dp * dp);
        tv.y = fmaf(-LMBDA * w, x4.y, tv.y);
        dq = qi - q1[k + 2]; dp = pi - p1[k + 2]; w = fmaf(dq, dq, dp * dp);
        tv.z = fmaf(-LMBDA * w, x4.z, tv.z);
        dq = qi - q1[k + 3]; dp = pi - p1[k + 3]; w = fmaf(dq, dq, dp * dp);
        tv.w = fmaf(-LMBDA * w, x4.w, tv.w);
      }
      Tt[kk + 0][i] = tv.x; Tt[kk + 1][i] = tv.y;
      Tt[kk + 2][i] = tv.z; Tt[kk + 3][i] = tv.w;
    }
#pragma unroll
    for (int l = 0; l < 4; ++l) {
      int f = t + (l << 8);
      int kk = f >> 5, jq = (f & 31) << 2;
      *(float4*)&Sv[kk][jq] = *(const float4*)(Si + (size_t)(k0 + kk) * K_ + jq);
    }
    __syncthreads();
#pragma unroll
    for (int kk = 0; kk < 32; ++kk) {
      const float4 a0 = *(const float4*)&Tt[kk][ir];
      const float4 a1 = *(const float4*)&Tt[kk][ir + 4];
      const float4 b0 = *(const float4*)&Sv[kk][jc];
      const float4 b1 = *(const float4*)&Sv[kk][jc + 4];
      const float av[8] = {a0.x, a0.y, a0.z, a0.w, a1.x, a1.y, a1.z, a1.w};
      const float bv[8] = {b0.x, b0.y, b0.z, b0.w, b1.x, b1.y, b1.z, b1.w};
#pragma unroll
      for (int i = 0; i < 8; ++i)
#pragma unroll
        for (int jx = 0; jx < 8; ++jx)
          acc[i][jx] = fmaf(av[i], bv[jx], acc[i][jx]);
    }
    __syncthreads();
  }

  float* __restrict__ O = Xout + (size_t)b * (K_ * K_);
#pragma unroll
  for (int i = 0; i < 8; ++i) {
    float4 o0 = {acc[i][0], acc[i][1], acc[i][2], acc[i][3]};
    float4 o1 = {acc[i][4], acc[i][5], acc[i][6], acc[i][7]};
    *(float4*)(O + (size_t)(ir + i) * K_ + jc) = o0;
    *(float4*)(O + (size_t)(ir + i) * K_ + jc + 4) = o1;
  }
}

// ---------------------------------------------------------------------------
extern "C" void kernel_launch(void* const* d_in, const int* in_sizes, int n_in,
                              void* d_out, int out_size, void* d_ws, size_t ws_size,
                              hipStream_t stream) {
  (void)in_sizes; (void)n_in; (void)out_size;
  const float* feat_x  = (const float*)d_in[0];
  const float* feat_y  = (const float*)d_in[1];
  const float* evals_x = (const float*)d_in[2];
  const float* evals_y = (const float*)d_in[3];
  const float* evtx    = (const float*)d_in[4];
  const float* evty    = (const float*)d_in[5];
  float* out = (float*)d_out;
  float* ws  = (float*)d_ws;

  const size_t KC16 = (size_t)16 * K_ * C_;  // 524288 floats (AB / one slab)
  const size_t KK   = (size_t)K_ * K_;       // 16384
  const size_t fixed = KC16 + 3 * (KK * B_) + 4096 + 2 * (KK * B_);
  const int T = N_ / 32;  // 625 k-steps total

  int S = 16, Sa = 16, chunk = 0;
  for (;;) {
    int steps = (T + S - 1) / S;
    chunk = steps * 32;
    Sa = (T + steps - 1) / steps;
    if (((size_t)Sa * KC16 + fixed) * sizeof(float) <= ws_size || S == 1) break;
    S >>= 1;
  }

  float* part = ws;
  float* AB   = part + (size_t)Sa * KC16;
  float* Sm   = AB + KC16;
  float* Rm   = Sm + KK * B_;
  float* Sinv = Rm + KK * B_;
  float* PQ   = Sinv + KK * B_;
  float* X0   = PQ + 4096;
  float* X1   = X0 + KK * B_;

  proj_mfma<<<dim3(2, Sa, 16), 512, 0, stream>>>(feat_x, feat_y, evtx, evty, part, Sa, chunk);
  reduce_parts<<<dim3((16 * K_ * C_ + 255) / 256), 256, 0, stream>>>(part, AB, Sa);
  gram_kernel<<<dim3(8, 2), 256, 0, stream>>>(AB, Sm, Rm);
  mask_prep<<<dim3(8), 128, 0, stream>>>(evals_x, evals_y, PQ);
  gj_inverse<<<dim3(8), 256, 0, stream>>>(Sm, Sinv);
  solve_iter<<<dim3(8), 256, 0, stream>>>(Rm, Sinv, PQ, X0, X0, 1);
  solve_iter<<<dim3(8), 256, 0, stream>>>(Rm, Sinv, PQ, X0, X1, 0);
  solve_iter<<<dim3(8), 256, 0, stream>>>(Rm, Sinv, PQ, X1, out, 0);
}

// Round 4
// 308.706 us; speedup vs baseline: 3.9673x; 1.1359x over previous
//
#include <hip/hip_runtime.h>
#include <math.h>

#define B_ 8
#define N_ 20000
#define K_ 128
#define C_ 256

static_assert(N_ % 32 == 0, "N must be multiple of 32");

constexpr float LMBDA = 100.0f;
constexpr float EPS_EV = 1e-10f;

typedef unsigned int u32x4 __attribute__((ext_vector_type(4)));
typedef short short8_t __attribute__((ext_vector_type(8)));
typedef float f32x4 __attribute__((ext_vector_type(4)));

// Split two fp32 into bf16 hi-plane (truncation; residual exact) and
// bf16 lo-plane (RNE of residual). Packed as (x1|x0) u32 words ready for
// bf16 LDS rows. ~6 VALU per 2 elements, no compute-loop repack needed.
static __device__ inline void split2(float x0, float x1, unsigned& h, unsigned& l) {
  unsigned u0 = __builtin_bit_cast(unsigned, x0);
  unsigned u1 = __builtin_bit_cast(unsigned, x1);
  h = __builtin_amdgcn_perm(u1, u0, 0x07060302u);  // top16(x1)<<16 | top16(x0)
  float r0 = x0 - __builtin_bit_cast(float, u0 & 0xFFFF0000u);  // exact
  float r1 = x1 - __builtin_bit_cast(float, u1 & 0xFFFF0000u);  // exact
  unsigned v0 = __builtin_bit_cast(unsigned, r0);
  unsigned v1 = __builtin_bit_cast(unsigned, r1);
  v0 += 0x7FFFu + ((v0 >> 16) & 1u);  // RNE to bf16
  v1 += 0x7FFFu + ((v1 >> 16) & 1u);
  l = __builtin_amdgcn_perm(v1, v0, 0x07060302u);
}

// ---------------------------------------------------------------------------
// Kernel 1: projection GEMM, bf16x3 split MFMA, separate-plane LDS.
// out[m,c] = sum_n E[m][n] * F[n][c].  Block 512 thr (8 waves: 4m x 2c),
// tile 128m x 128c, K-step 32 n. LDS rows stride 40 bf16 (80 B) ->
// granule class (5*row+lg) mod 8 uniform: conflict-free b128 reads/writes.
// ---------------------------------------------------------------------------
__global__ __launch_bounds__(512, 4)
void proj_mfma(const float* __restrict__ feat_x, const float* __restrict__ feat_y,
               const float* __restrict__ evx, const float* __restrict__ evy,
               float* __restrict__ part, int Sa, int chunk) {
  const int bm = blockIdx.z;
  const int b = bm >> 1, mat = bm & 1;
  const float* __restrict__ E = (mat ? evy : evx) + (size_t)b * K_ * N_;
  const float* __restrict__ F = (mat ? feat_y : feat_x) + (size_t)b * N_ * C_;
  const int c0 = blockIdx.x << 7;
  const int s = blockIdx.y;
  const int nb = s * chunk;
  const int ne = min(N_, nb + chunk);
  const int nt = (ne - nb) >> 5;

  __shared__ unsigned short Ah[128][40];
  __shared__ unsigned short Al[128][40];
  __shared__ unsigned short Bh[128][40];
  __shared__ unsigned short Bl[128][40];

  const int t = threadIdx.x;
  const int lane = t & 63, wv = t >> 6;
  const int wm = wv & 3;          // m-tile 0..3 (32 rows each)
  const int wcc = wv >> 2;        // c-tile 0..1 (64 cols each)
  const int lr = lane & 15, lg = lane >> 4;
  const int k0 = lg << 3;

  // staging maps
  const int am = t >> 2, ak = (t & 3) << 3;          // A: row am, k ak..ak+7
  const int cl = t & 127, gq = (t >> 7) << 2;        // B: col cl, n quads gq, gq+16

  f32x4 acc[2][4];
#pragma unroll
  for (int i = 0; i < 2; ++i)
#pragma unroll
    for (int j = 0; j < 4; ++j) acc[i][j] = (f32x4){0.f, 0.f, 0.f, 0.f};

  float4 pa0, pa1;
  float pb[8];
  {
    const float* ep = E + (size_t)am * N_ + nb + ak;
    pa0 = *(const float4*)ep;
    pa1 = *(const float4*)(ep + 4);
#pragma unroll
    for (int i = 0; i < 4; ++i) {
      pb[i]     = F[(size_t)(nb + gq + i) * C_ + c0 + cl];
      pb[4 + i] = F[(size_t)(nb + gq + 16 + i) * C_ + c0 + cl];
    }
  }

  for (int it = 0; it < nt; ++it) {
    __syncthreads();  // LDS free
    {
      unsigned h01, l01, h23, l23, h45, l45, h67, l67;
      split2(pa0.x, pa0.y, h01, l01);
      split2(pa0.z, pa0.w, h23, l23);
      split2(pa1.x, pa1.y, h45, l45);
      split2(pa1.z, pa1.w, h67, l67);
      *(u32x4*)&Ah[am][ak] = (u32x4){h01, h23, h45, h67};
      *(u32x4*)&Al[am][ak] = (u32x4){l01, l23, l45, l67};
      split2(pb[0], pb[1], h01, l01);
      split2(pb[2], pb[3], h23, l23);
      *(uint2*)&Bh[cl][gq] = (uint2){h01, h23};
      *(uint2*)&Bl[cl][gq] = (uint2){l01, l23};
      split2(pb[4], pb[5], h45, l45);
      split2(pb[6], pb[7], h67, l67);
      *(uint2*)&Bh[cl][gq + 16] = (uint2){h45, h67};
      *(uint2*)&Bl[cl][gq + 16] = (uint2){l45, l67};
    }
    if (it + 1 < nt) {
      const int n0 = nb + ((it + 1) << 5);
      const float* ep = E + (size_t)am * N_ + n0 + ak;
      pa0 = *(const float4*)ep;
      pa1 = *(const float4*)(ep + 4);
#pragma unroll
      for (int i = 0; i < 4; ++i) {
        pb[i]     = F[(size_t)(n0 + gq + i) * C_ + c0 + cl];
        pb[4 + i] = F[(size_t)(n0 + gq + 16 + i) * C_ + c0 + cl];
      }
    }
    __syncthreads();  // LDS ready

    short8_t a_h[2], a_l[2];
#pragma unroll
    for (int mt = 0; mt < 2; ++mt) {
      const int m = (wm << 5) + (mt << 4) + lr;
      a_h[mt] = *(const short8_t*)&Ah[m][k0];
      a_l[mt] = *(const short8_t*)&Al[m][k0];
    }
#pragma unroll
    for (int ct = 0; ct < 4; ++ct) {
      const int c = (wcc << 6) + (ct << 4) + lr;
      const short8_t b_h = *(const short8_t*)&Bh[c][k0];
      const short8_t b_l = *(const short8_t*)&Bl[c][k0];
#pragma unroll
      for (int mt = 0; mt < 2; ++mt) {
        acc[mt][ct] = __builtin_amdgcn_mfma_f32_16x16x32_bf16(a_h[mt], b_h, acc[mt][ct], 0, 0, 0);
        acc[mt][ct] = __builtin_amdgcn_mfma_f32_16x16x32_bf16(a_l[mt], b_h, acc[mt][ct], 0, 0, 0);
        acc[mt][ct] = __builtin_amdgcn_mfma_f32_16x16x32_bf16(a_h[mt], b_l, acc[mt][ct], 0, 0, 0);
      }
    }
  }

  // epilogue: C/D layout col=lane&15, row=(lane>>4)*4+r
  float* __restrict__ P = part + ((size_t)bm * Sa + s) * (K_ * C_);
#pragma unroll
  for (int mt = 0; mt < 2; ++mt)
#pragma unroll
    for (int ct = 0; ct < 4; ++ct) {
      const int ccol = c0 + (wcc << 6) + (ct << 4) + lr;
#pragma unroll
      for (int r = 0; r < 4; ++r) {
        const int mrow = (wm << 5) + (mt << 4) + (lg << 2) + r;
        P[(size_t)mrow * C_ + ccol] = acc[mt][ct][r];
      }
    }
}

// ---------------------------------------------------------------------------
// Kernel 2: reduce split-n partials -> AB
// ---------------------------------------------------------------------------
__global__ void reduce_parts(const float* __restrict__ part, float* __restrict__ AB, int Sa) {
  int idx = blockIdx.x * 256 + threadIdx.x;
  if (idx >= 16 * K_ * C_) return;
  int bm = idx / (K_ * C_);
  int rem = idx - bm * (K_ * C_);
  float v = 0.f;
  for (int s = 0; s < Sa; ++s) v += part[((size_t)bm * Sa + s) * (K_ * C_) + rem];
  AB[idx] = v;
}

// ---------------------------------------------------------------------------
// Kernel 3: gram matrices, 64x64 quadrant per block (8 x 2 x 4 grid).
// which=0: Sm = A A^T + 1e-8 I ; which=1: Rm = Bm A^T
// ---------------------------------------------------------------------------
__global__ __launch_bounds__(256)
void gram_kernel(const float* __restrict__ AB, float* __restrict__ Sm, float* __restrict__ Rm) {
  const int b = blockIdx.x, which = blockIdx.y, qz = blockIdx.z;
  const int iq = (qz & 1) << 6, jq = (qz >> 1) << 6;
  const float* __restrict__ L  = AB + ((size_t)(b * 2 + which)) * (K_ * C_);
  const float* __restrict__ Ar = AB + ((size_t)(b * 2)) * (K_ * C_);
  float* __restrict__ out = (which ? Rm : Sm) + (size_t)b * (K_ * K_);
  const int t = threadIdx.x;
  const int ir = iq + ((t >> 4) << 2), jc = jq + ((t & 15) << 2);
  float acc[4][4] = {};
  for (int c0 = 0; c0 < C_; c0 += 4) {
    float4 li[4], rj[4];
#pragma unroll
    for (int i = 0; i < 4; ++i) li[i] = *(const float4*)(L + (size_t)(ir + i) * C_ + c0);
#pragma unroll
    for (int j = 0; j < 4; ++j) rj[j] = *(const float4*)(Ar + (size_t)(jc + j) * C_ + c0);
#pragma unroll
    for (int i = 0; i < 4; ++i)
#pragma unroll
      for (int j = 0; j < 4; ++j)
        acc[i][j] += li[i].x * rj[j].x + li[i].y * rj[j].y +
                     li[i].z * rj[j].z + li[i].w * rj[j].w;
  }
#pragma unroll
  for (int i = 0; i < 4; ++i)
#pragma unroll
    for (int j = 0; j < 4; ++j) {
      float v = acc[i][j];
      if (!which && (ir + i) == (jc + j)) v += 1e-8f;
      out[(size_t)(ir + i) * K_ + (jc + j)] = v;
    }
}

// ---------------------------------------------------------------------------
// Kernel 4: mask prep -> q1,p1 (cols, evals_x), q2,p2 (rows, evals_y)
// ---------------------------------------------------------------------------
__global__ void mask_prep(const float* __restrict__ evx, const float* __restrict__ evy,
                          float* __restrict__ PQ) {
  const int b = blockIdx.x, t = threadIdx.x;  // 128 threads
  float e1 = evx[b * K_ + t];
  float e2 = evy[b * K_ + t];
  if (e1 != e1) e1 = EPS_EV;
  if (e2 != e2) e2 = EPS_EV;
  e1 = fminf(fmaxf(e1, EPS_EV), 1e6f);
  e2 = fminf(fmaxf(e2, EPS_EV), 1e6f);

  __shared__ float wmax[2];
  float v = fmaxf(e1, e2);
#pragma unroll
  for (int d = 1; d < 64; d <<= 1) v = fmaxf(v, __shfl_xor(v, d, 64));
  if ((t & 63) == 0) wmax[t >> 6] = v;
  __syncthreads();
  const float scale = fmaxf(fmaxf(wmax[0], wmax[1]), 1e-10f);

  const float g1 = sqrtf(e1 / scale);
  const float g2 = sqrtf(e2 / scale);
  const float d1 = fmaf(g1, g1, 1.f);
  const float d2 = fmaf(g2, g2, 1.f);
  float* P = PQ + b * 512;
  P[t]       = g1 / d1;
  P[128 + t] = 1.f / d1;
  P[256 + t] = g2 / d2;
  P[384 + t] = 1.f / d2;
}

// ---------------------------------------------------------------------------
// Kernel 5: BLOCKED Gauss-Jordan inverse (SPD), 16x16 pivot panels.
// (unchanged from round 3 — went from 964us to off-the-radar)
// ---------------------------------------------------------------------------
__global__ __launch_bounds__(256)
void gj_inverse(const float* __restrict__ Sm, float* __restrict__ Sinv) {
  const int b = blockIdx.x, t = threadIdx.x;
  __shared__ float a[K_ * 132];
  __shared__ float Pi[16 * 20];
  __shared__ float Rp[16 * 132];
  __shared__ float Cp[K_ * 20];
  const float* __restrict__ Sb = Sm + (size_t)b * (K_ * K_);
#pragma unroll
  for (int l = 0; l < 16; ++l) {
    int f = t + (l << 8);
    int i = f >> 5, j = (f & 31) << 2;
    *(float4*)&a[i * 132 + j] = *(const float4*)(Sb + i * K_ + j);
  }
  __syncthreads();

  const int j = t & 127, h = t >> 7;
  const int lane = t & 63;

  for (int p = 0; p < 8; ++p) {
    const int pb = p << 4;

    if (t < 64) {
      const int r = lane & 15, g = lane >> 4;
      float4 v4 = *(const float4*)&a[(pb + r) * 132 + pb + (g << 2)];
      float vv[4] = {v4.x, v4.y, v4.z, v4.w};
#pragma unroll
      for (int k = 0; k < 16; ++k) {
        const int srcrow = (lane & 48) | k;
        float rk[4];
        rk[0] = __shfl(vv[0], srcrow);
        rk[1] = __shfl(vv[1], srcrow);
        rk[2] = __shfl(vv[2], srcrow);
        rk[3] = __shfl(vv[3], srcrow);
        const int kg = (k >> 2) << 4;
        const float pv = __shfl(vv[k & 3], kg | k);
        const float c  = __shfl(vv[k & 3], kg | r);
        const float pr = 1.0f / pv;
        float rs[4];
#pragma unroll
        for (int e = 0; e < 4; ++e) rs[e] = rk[e] * pr;
        if (r == k) {
#pragma unroll
          for (int e = 0; e < 4; ++e) vv[e] = rs[e];
          if (g == (k >> 2)) vv[k & 3] = pr;
        } else {
#pragma unroll
          for (int e = 0; e < 4; ++e) vv[e] = fmaf(-c, rs[e], vv[e]);
          if (g == (k >> 2)) vv[k & 3] = -c * pr;
        }
      }
      Pi[r * 20 + (g << 2) + 0] = vv[0];
      Pi[r * 20 + (g << 2) + 1] = vv[1];
      Pi[r * 20 + (g << 2) + 2] = vv[2];
      Pi[r * 20 + (g << 2) + 3] = vv[3];
    }
    __syncthreads();

    {
      float Ak[16];
#pragma unroll
      for (int k = 0; k < 16; ++k) Ak[k] = a[(pb + k) * 132 + j];
      const unsigned jj = (unsigned)(j - pb);
      const int r0 = h << 3;
#pragma unroll
      for (int q = 0; q < 8; ++q) {
        const int r = r0 + q;
        float acc = 0.f;
#pragma unroll
        for (int k = 0; k < 16; ++k) acc = fmaf(Pi[r * 20 + k], Ak[k], acc);
        Rp[r * 132 + j] = (jj < 16u) ? Pi[r * 20 + jj] : acc;
      }
      const int i = j;
      const int cb = h << 3;
      float4 cA = *(const float4*)&a[i * 132 + pb + cb];
      float4 cB = *(const float4*)&a[i * 132 + pb + cb + 4];
      *(float4*)&Cp[i * 20 + cb] = cA;
      *(float4*)&Cp[i * 20 + cb + 4] = cB;
    }
    __syncthreads();

    {
      float Rk[16];
#pragma unroll
      for (int k = 0; k < 16; ++k) Rk[k] = Rp[k * 132 + j];
      const unsigned jj = (unsigned)(j - pb);
      const int i0 = h << 6;
#pragma unroll 4
      for (int m = 0; m < 64; ++m) {
        const int i = i0 + m;
        const float4 c0 = *(const float4*)&Cp[i * 20];
        const float4 c1 = *(const float4*)&Cp[i * 20 + 4];
        const float4 c2 = *(const float4*)&Cp[i * 20 + 8];
        const float4 c3 = *(const float4*)&Cp[i * 20 + 12];
        float u0 = c0.x * Rk[0] + c0.y * Rk[1] + c0.z * Rk[2] + c0.w * Rk[3];
        float u1 = c1.x * Rk[4] + c1.y * Rk[5] + c1.z * Rk[6] + c1.w * Rk[7];
        float u2 = c2.x * Rk[8] + c2.y * Rk[9] + c2.z * Rk[10] + c2.w * Rk[11];
        float u3 = c3.x * Rk[12] + c3.y * Rk[13] + c3.z * Rk[14] + c3.w * Rk[15];
        const float upd = (u0 + u1) + (u2 + u3);
        const unsigned ii = (unsigned)(i - pb);
        float newv;
        if (ii < 16u) {
          newv = Rk[ii];
        } else {
          const float base = (jj < 16u) ? 0.f : a[i * 132 + j];
          newv = base - upd;
        }
        a[i * 132 + j] = newv;
      }
    }
    __syncthreads();
  }

  float* __restrict__ O = Sinv + (size_t)b * (K_ * K_);
#pragma unroll
  for (int l = 0; l < 16; ++l) {
    int f = t + (l << 8);
    int i = f >> 5, jq = (f & 31) << 2;
    *(float4*)(O + i * K_ + jq) = *(const float4*)&a[i * 132 + jq];
  }
}

// ---------------------------------------------------------------------------
// Kernel 6: Neumann iteration, 2 blocks per batch (64 rows each).
// Xout = (R - W .* Xin) @ Sinv ; W[i,k]=LMBDA*((q2i-q1k)^2+(p2i-p1k)^2)
// ---------------------------------------------------------------------------
__global__ __launch_bounds__(256)
void solve_iter(const float* __restrict__ Rm, const float* __restrict__ Sinv,
                const float* __restrict__ PQ, const float* __restrict__ Xin,
                float* __restrict__ Xout, const int first) {
  const int bb = blockIdx.x;
  const int b = bb >> 1, rb = (bb & 1) << 6;
  const int t = threadIdx.x;
  __shared__ float Tt[32][68];   // [kk][i_loc], 68: 16B-aligned rows, 4-way wr max
  __shared__ float Sv[32][132];  // [kk][j]
  __shared__ float q1[K_], p1[K_], q2l[64], p2l[64];
  {
    const float* P = PQ + b * 512;
    if (t < K_) { q1[t] = P[t]; p1[t] = P[128 + t]; }
    if (t < 64) { q2l[t] = P[256 + rb + t]; p2l[t] = P[384 + rb + t]; }
  }
  __syncthreads();
  const float* __restrict__ Rb = Rm + (size_t)b * (K_ * K_);
  const float* __restrict__ Xb = Xin + (size_t)b * (K_ * K_);
  const float* __restrict__ Si = Sinv + (size_t)b * (K_ * K_);
  const int ir = (t >> 4) << 2, jc = (t & 15) << 3;
  float acc[4][8] = {};

  for (int k0 = 0; k0 < K_; k0 += 32) {
#pragma unroll
    for (int l = 0; l < 2; ++l) {
      int f = t + (l << 8);
      int i = f >> 3;                 // 0..63
      int kk = (f & 7) << 2;
      const int k = k0 + kk;
      const int gi = rb + i;
      float4 tv = *(const float4*)(Rb + (size_t)gi * K_ + k);
      if (!first) {
        const float4 x4 = *(const float4*)(Xb + (size_t)gi * K_ + k);
        const float qi = q2l[i], pi = p2l[i];
        float dq, dp, w;
        dq = qi - q1[k + 0]; dp = pi - p1[k + 0]; w = fmaf(dq, dq, dp * dp);
        tv.x = fmaf(-LMBDA * w, x4.x, tv.x);
        dq = qi - q1[k + 1]; dp = pi - p1[k + 1]; w = fmaf(dq, dq, dp * dp);
        tv.y = fmaf(-LMBDA * w, x4.y, tv.y);
        dq = qi - q1[k + 2]; dp = pi - p1[k + 2]; w = fmaf(dq, dq, dp * dp);
        tv.z = fmaf(-LMBDA * w, x4.z, tv.z);
        dq = qi - q1[k + 3]; dp = pi - p1[k + 3]; w = fmaf(dq, dq, dp * dp);
        tv.w = fmaf(-LMBDA * w, x4.w, tv.w);
      }
      Tt[kk + 0][i] = tv.x; Tt[kk + 1][i] = tv.y;
      Tt[kk + 2][i] = tv.z; Tt[kk + 3][i] = tv.w;
    }
#pragma unroll
    for (int l = 0; l < 4; ++l) {
      int f = t + (l << 8);
      int kk = f >> 5, j4 = (f & 31) << 2;
      *(float4*)&Sv[kk][j4] = *(const float4*)(Si + (size_t)(k0 + kk) * K_ + j4);
    }
    __syncthreads();
#pragma unroll
    for (int kk = 0; kk < 32; ++kk) {
      const float4 a4 = *(const float4*)&Tt[kk][ir];
      const float4 b0 = *(const float4*)&Sv[kk][jc];
      const float4 b1 = *(const float4*)&Sv[kk][jc + 4];
      const float av[4] = {a4.x, a4.y, a4.z, a4.w};
      const float bv[8] = {b0.x, b0.y, b0.z, b0.w, b1.x, b1.y, b1.z, b1.w};
#pragma unroll
      for (int i = 0; i < 4; ++i)
#pragma unroll
        for (int jx = 0; jx < 8; ++jx)
          acc[i][jx] = fmaf(av[i], bv[jx], acc[i][jx]);
    }
    __syncthreads();
  }

  float* __restrict__ O = Xout + (size_t)b * (K_ * K_);
#pragma unroll
  for (int i = 0; i < 4; ++i) {
    float4 o0 = {acc[i][0], acc[i][1], acc[i][2], acc[i][3]};
    float4 o1 = {acc[i][4], acc[i][5], acc[i][6], acc[i][7]};
    *(float4*)(O + (size_t)(rb + ir + i) * K_ + jc) = o0;
    *(float4*)(O + (size_t)(rb + ir + i) * K_ + jc + 4) = o1;
  }
}

// ---------------------------------------------------------------------------
extern "C" void kernel_launch(void* const* d_in, const int* in_sizes, int n_in,
                              void* d_out, int out_size, void* d_ws, size_t ws_size,
                              hipStream_t stream) {
  (void)in_sizes; (void)n_in; (void)out_size;
  const float* feat_x  = (const float*)d_in[0];
  const float* feat_y  = (const float*)d_in[1];
  const float* evals_x = (const float*)d_in[2];
  const float* evals_y = (const float*)d_in[3];
  const float* evtx    = (const float*)d_in[4];
  const float* evty    = (const float*)d_in[5];
  float* out = (float*)d_out;
  float* ws  = (float*)d_ws;

  const size_t KC16 = (size_t)16 * K_ * C_;  // 524288 floats
  const size_t KK   = (size_t)K_ * K_;       // 16384
  const size_t fixed = KC16 + 3 * (KK * B_) + 4096 + 2 * (KK * B_);
  const int T = N_ / 32;  // 625 k-steps total

  int S = 32, Sa = 32, chunk = 0;
  for (;;) {
    int steps = (T + S - 1) / S;
    chunk = steps * 32;
    Sa = (T + steps - 1) / steps;  // active slabs, all with nb < N_
    if (((size_t)Sa * KC16 + fixed) * sizeof(float) <= ws_size || S == 1) break;
    S >>= 1;
  }

  float* part = ws;
  float* AB   = part + (size_t)Sa * KC16;
  float* Sm   = AB + KC16;
  float* Rm   = Sm + KK * B_;
  float* Sinv = Rm + KK * B_;
  float* PQ   = Sinv + KK * B_;
  float* X0   = PQ + 4096;
  float* X1   = X0 + KK * B_;

  proj_mfma<<<dim3(2, Sa, 16), 512, 0, stream>>>(feat_x, feat_y, evtx, evty, part, Sa, chunk);
  reduce_parts<<<dim3((16 * K_ * C_ + 255) / 256), 256, 0, stream>>>(part, AB, Sa);
  gram_kernel<<<dim3(8, 2, 4), 256, 0, stream>>>(AB, Sm, Rm);
  mask_prep<<<dim3(8), 128, 0, stream>>>(evals_x, evals_y, PQ);
  gj_inverse<<<dim3(8), 256, 0, stream>>>(Sm, Sinv);
  solve_iter<<<dim3(16), 256, 0, stream>>>(Rm, Sinv, PQ, X0, X0, 1);
  solve_iter<<<dim3(16), 256, 0, stream>>>(Rm, Sinv, PQ, X0, X1, 0);
  solve_iter<<<dim3(16), 256, 0, stream>>>(Rm, Sinv, PQ, X1, out, 0);
}

// Round 5
// 256.476 us; speedup vs baseline: 4.7753x; 1.2036x over previous
//
#include <hip/hip_runtime.h>
#include <math.h>

#define B_ 8
#define N_ 20000
#define K_ 128
#define C_ 256

static_assert(N_ % 32 == 0, "N must be multiple of 32");

constexpr float LMBDA = 100.0f;
constexpr float EPS_EV = 1e-10f;

typedef unsigned int u32x4 __attribute__((ext_vector_type(4)));
typedef short short8_t __attribute__((ext_vector_type(8)));
typedef float f32x4 __attribute__((ext_vector_type(4)));

// Split two fp32 into bf16 hi-plane (truncation; residual exact) and
// bf16 lo-plane (RNE of residual). Packed as (x1|x0) u32 words.
static __device__ inline void split2(float x0, float x1, unsigned& h, unsigned& l) {
  unsigned u0 = __builtin_bit_cast(unsigned, x0);
  unsigned u1 = __builtin_bit_cast(unsigned, x1);
  h = __builtin_amdgcn_perm(u1, u0, 0x07060302u);  // top16(x1)<<16 | top16(x0)
  float r0 = x0 - __builtin_bit_cast(float, u0 & 0xFFFF0000u);  // exact
  float r1 = x1 - __builtin_bit_cast(float, u1 & 0xFFFF0000u);  // exact
  unsigned v0 = __builtin_bit_cast(unsigned, r0);
  unsigned v1 = __builtin_bit_cast(unsigned, r1);
  v0 += 0x7FFFu + ((v0 >> 16) & 1u);  // RNE to bf16
  v1 += 0x7FFFu + ((v1 >> 16) & 1u);
  l = __builtin_amdgcn_perm(v1, v0, 0x07060302u);
}

// ---------------------------------------------------------------------------
// Kernel 1: projection GEMM, bf16x3 split MFMA, separate-plane LDS,
// 2-deep register prefetch (loads for tile t+2 issued at iter t -> ~2
// iterations of latency cover, no per-step vmcnt stall).
// ---------------------------------------------------------------------------
__global__ __launch_bounds__(512, 2)
void proj_mfma(const float* __restrict__ feat_x, const float* __restrict__ feat_y,
               const float* __restrict__ evx, const float* __restrict__ evy,
               float* __restrict__ part, int Sa, int chunk) {
  const int bm = blockIdx.z;
  const int b = bm >> 1, mat = bm & 1;
  const float* __restrict__ E = (mat ? evy : evx) + (size_t)b * K_ * N_;
  const float* __restrict__ F = (mat ? feat_y : feat_x) + (size_t)b * N_ * C_;
  const int c0 = blockIdx.x << 7;
  const int s = blockIdx.y;
  const int nb = s * chunk;
  const int ne = min(N_, nb + chunk);
  const int nt = (ne - nb) >> 5;

  __shared__ unsigned short Ah[128][40];
  __shared__ unsigned short Al[128][40];
  __shared__ unsigned short Bh[128][40];
  __shared__ unsigned short Bl[128][40];

  const int t = threadIdx.x;
  const int lane = t & 63, wv = t >> 6;
  const int wm = wv & 3;          // m-tile 0..3 (32 rows each)
  const int wcc = wv >> 2;        // c-tile 0..1 (64 cols each)
  const int lr = lane & 15, lg = lane >> 4;
  const int k0 = lg << 3;

  // staging maps
  const int am = t >> 2, ak = (t & 3) << 3;      // A: row am, k ak..ak+7
  const int cl = t & 127, gq = (t >> 7) << 2;    // B: col cl, n quads gq, gq+16

  f32x4 acc[2][4];
#pragma unroll
  for (int i = 0; i < 2; ++i)
#pragma unroll
    for (int j = 0; j < 4; ++j) acc[i][j] = (f32x4){0.f, 0.f, 0.f, 0.f};

  struct Stage { float4 a0, a1; float b0, b1, b2, b3, b4, b5, b6, b7; };

  auto LOAD = [&](Stage& st, int n0) {
    const float* ep = E + (size_t)am * N_ + n0 + ak;
    st.a0 = *(const float4*)ep;
    st.a1 = *(const float4*)(ep + 4);
    const float* fp = F + (size_t)(n0 + gq) * C_ + c0 + cl;
    st.b0 = fp[0];
    st.b1 = fp[C_];
    st.b2 = fp[2 * C_];
    st.b3 = fp[3 * C_];
    const float* fp2 = fp + (size_t)16 * C_;
    st.b4 = fp2[0];
    st.b5 = fp2[C_];
    st.b6 = fp2[2 * C_];
    st.b7 = fp2[3 * C_];
  };

  auto WRITE = [&](Stage& st) {
    unsigned h01, l01, h23, l23, h45, l45, h67, l67;
    split2(st.a0.x, st.a0.y, h01, l01);
    split2(st.a0.z, st.a0.w, h23, l23);
    split2(st.a1.x, st.a1.y, h45, l45);
    split2(st.a1.z, st.a1.w, h67, l67);
    *(u32x4*)&Ah[am][ak] = (u32x4){h01, h23, h45, h67};
    *(u32x4*)&Al[am][ak] = (u32x4){l01, l23, l45, l67};
    split2(st.b0, st.b1, h01, l01);
    split2(st.b2, st.b3, h23, l23);
    *(uint2*)&Bh[cl][gq] = (uint2){h01, h23};
    *(uint2*)&Bl[cl][gq] = (uint2){l01, l23};
    split2(st.b4, st.b5, h45, l45);
    split2(st.b6, st.b7, h67, l67);
    *(uint2*)&Bh[cl][gq + 16] = (uint2){h45, h67};
    *(uint2*)&Bl[cl][gq + 16] = (uint2){l45, l67};
  };

  auto COMPUTE = [&]() {
    short8_t a_h[2], a_l[2];
#pragma unroll
    for (int mt = 0; mt < 2; ++mt) {
      const int m = (wm << 5) + (mt << 4) + lr;
      a_h[mt] = *(const short8_t*)&Ah[m][k0];
      a_l[mt] = *(const short8_t*)&Al[m][k0];
    }
#pragma unroll
    for (int ct = 0; ct < 4; ++ct) {
      const int c = (wcc << 6) + (ct << 4) + lr;
      const short8_t b_h = *(const short8_t*)&Bh[c][k0];
      const short8_t b_l = *(const short8_t*)&Bl[c][k0];
#pragma unroll
      for (int mt = 0; mt < 2; ++mt) {
        acc[mt][ct] = __builtin_amdgcn_mfma_f32_16x16x32_bf16(a_h[mt], b_h, acc[mt][ct], 0, 0, 0);
        acc[mt][ct] = __builtin_amdgcn_mfma_f32_16x16x32_bf16(a_l[mt], b_h, acc[mt][ct], 0, 0, 0);
        acc[mt][ct] = __builtin_amdgcn_mfma_f32_16x16x32_bf16(a_h[mt], b_l, acc[mt][ct], 0, 0, 0);
      }
    }
  };

  Stage sA, sB;
  LOAD(sA, nb);
  if (nt > 1) LOAD(sB, nb + 32);

  for (int it = 0; it < nt; it += 2) {
    __syncthreads();            // LDS free
    WRITE(sA);                  // vmcnt wait lands here, issued 2 iters ago
    if (it + 2 < nt) LOAD(sA, nb + ((it + 2) << 5));
    __syncthreads();            // LDS ready
    COMPUTE();
    if (it + 1 < nt) {
      __syncthreads();
      WRITE(sB);
      if (it + 3 < nt) LOAD(sB, nb + ((it + 3) << 5));
      __syncthreads();
      COMPUTE();
    }
  }

  // epilogue: C/D layout col=lane&15, row=(lane>>4)*4+r
  float* __restrict__ P = part + ((size_t)bm * Sa + s) * (K_ * C_);
#pragma unroll
  for (int mt = 0; mt < 2; ++mt)
#pragma unroll
    for (int ct = 0; ct < 4; ++ct) {
      const int ccol = c0 + (wcc << 6) + (ct << 4) + lr;
#pragma unroll
      for (int r = 0; r < 4; ++r) {
        const int mrow = (wm << 5) + (mt << 4) + (lg << 2) + r;
        P[(size_t)mrow * C_ + ccol] = acc[mt][ct][r];
      }
    }
}

// ---------------------------------------------------------------------------
// Kernel 2: reduce split-n partials -> AB (float4 vectorized)
// ---------------------------------------------------------------------------
__global__ void reduce_parts(const float* __restrict__ part, float* __restrict__ AB, int Sa) {
  const int idx4 = blockIdx.x * 256 + threadIdx.x;       // float4 units
  if (idx4 >= 16 * K_ * C_ / 4) return;
  const int per = K_ * C_ / 4;
  const int bm = idx4 / per;
  const int rem4 = idx4 - bm * per;
  float4 v = {0.f, 0.f, 0.f, 0.f};
  for (int s = 0; s < Sa; ++s) {
    const float4 p = *(const float4*)&part[((size_t)bm * Sa + s) * (K_ * C_) + rem4 * 4];
    v.x += p.x; v.y += p.y; v.z += p.z; v.w += p.w;
  }
  *(float4*)&AB[(size_t)idx4 * 4] = v;
}

// ---------------------------------------------------------------------------
// Kernel 3: gram matrices, 64x64 quadrant per block (8 x 2 x 4 grid).
// which=0: Sm = A A^T + 1e-8 I ; which=1: Rm = Bm A^T
// ---------------------------------------------------------------------------
__global__ __launch_bounds__(256)
void gram_kernel(const float* __restrict__ AB, float* __restrict__ Sm, float* __restrict__ Rm) {
  const int b = blockIdx.x, which = blockIdx.y, qz = blockIdx.z;
  const int iq = (qz & 1) << 6, jq = (qz >> 1) << 6;
  const float* __restrict__ L  = AB + ((size_t)(b * 2 + which)) * (K_ * C_);
  const float* __restrict__ Ar = AB + ((size_t)(b * 2)) * (K_ * C_);
  float* __restrict__ out = (which ? Rm : Sm) + (size_t)b * (K_ * K_);
  const int t = threadIdx.x;
  const int ir = iq + ((t >> 4) << 2), jc = jq + ((t & 15) << 2);
  float acc[4][4] = {};
  for (int c0 = 0; c0 < C_; c0 += 4) {
    float4 li[4], rj[4];
#pragma unroll
    for (int i = 0; i < 4; ++i) li[i] = *(const float4*)(L + (size_t)(ir + i) * C_ + c0);
#pragma unroll
    for (int j = 0; j < 4; ++j) rj[j] = *(const float4*)(Ar + (size_t)(jc + j) * C_ + c0);
#pragma unroll
    for (int i = 0; i < 4; ++i)
#pragma unroll
      for (int j = 0; j < 4; ++j)
        acc[i][j] += li[i].x * rj[j].x + li[i].y * rj[j].y +
                     li[i].z * rj[j].z + li[i].w * rj[j].w;
  }
#pragma unroll
  for (int i = 0; i < 4; ++i)
#pragma unroll
    for (int j = 0; j < 4; ++j) {
      float v = acc[i][j];
      if (!which && (ir + i) == (jc + j)) v += 1e-8f;
      out[(size_t)(ir + i) * K_ + (jc + j)] = v;
    }
}

// ---------------------------------------------------------------------------
// Kernel 4: mask prep -> q1,p1 (cols, evals_x), q2,p2 (rows, evals_y)
// ---------------------------------------------------------------------------
__global__ void mask_prep(const float* __restrict__ evx, const float* __restrict__ evy,
                          float* __restrict__ PQ) {
  const int b = blockIdx.x, t = threadIdx.x;  // 128 threads
  float e1 = evx[b * K_ + t];
  float e2 = evy[b * K_ + t];
  if (e1 != e1) e1 = EPS_EV;
  if (e2 != e2) e2 = EPS_EV;
  e1 = fminf(fmaxf(e1, EPS_EV), 1e6f);
  e2 = fminf(fmaxf(e2, EPS_EV), 1e6f);

  __shared__ float wmax[2];
  float v = fmaxf(e1, e2);
#pragma unroll
  for (int d = 1; d < 64; d <<= 1) v = fmaxf(v, __shfl_xor(v, d, 64));
  if ((t & 63) == 0) wmax[t >> 6] = v;
  __syncthreads();
  const float scale = fmaxf(fmaxf(wmax[0], wmax[1]), 1e-10f);

  const float g1 = sqrtf(e1 / scale);
  const float g2 = sqrtf(e2 / scale);
  const float d1 = fmaf(g1, g1, 1.f);
  const float d2 = fmaf(g2, g2, 1.f);
  float* P = PQ + b * 512;
  P[t]       = g1 / d1;
  P[128 + t] = 1.f / d1;
  P[256 + t] = g2 / d2;
  P[384 + t] = 1.f / d2;
}

// ---------------------------------------------------------------------------
// Kernel 5: BLOCKED Gauss-Jordan inverse (SPD), 16x16 pivot panels,
// 512 threads (phase-2/3 per-thread work halved vs round 4).
// ---------------------------------------------------------------------------
__global__ __launch_bounds__(512)
void gj_inverse(const float* __restrict__ Sm, float* __restrict__ Sinv) {
  const int b = blockIdx.x, t = threadIdx.x;
  __shared__ float a[K_ * 132];
  __shared__ float Pi[16 * 20];
  __shared__ float Rp[16 * 132];
  __shared__ float Cp[K_ * 20];
  const float* __restrict__ Sb = Sm + (size_t)b * (K_ * K_);
#pragma unroll
  for (int l = 0; l < 8; ++l) {
    int f = t + (l << 9);
    int i = f >> 5, j = (f & 31) << 2;
    *(float4*)&a[i * 132 + j] = *(const float4*)(Sb + i * K_ + j);
  }
  __syncthreads();

  const int j = t & 127, rr = t >> 7;   // rr in 0..3
  const int lane = t & 63;

  for (int p = 0; p < 8; ++p) {
    const int pb = p << 4;

    // ---- phase 1: wave 0 inverts the 16x16 pivot block in registers ----
    if (t < 64) {
      const int r = lane & 15, g = lane >> 4;
      float4 v4 = *(const float4*)&a[(pb + r) * 132 + pb + (g << 2)];
      float vv[4] = {v4.x, v4.y, v4.z, v4.w};
#pragma unroll
      for (int k = 0; k < 16; ++k) {
        const int srcrow = (lane & 48) | k;
        float rk[4];
        rk[0] = __shfl(vv[0], srcrow);
        rk[1] = __shfl(vv[1], srcrow);
        rk[2] = __shfl(vv[2], srcrow);
        rk[3] = __shfl(vv[3], srcrow);
        const int kg = (k >> 2) << 4;
        const float pv = __shfl(vv[k & 3], kg | k);
        const float c  = __shfl(vv[k & 3], kg | r);
        const float pr = 1.0f / pv;
        float rs[4];
#pragma unroll
        for (int e = 0; e < 4; ++e) rs[e] = rk[e] * pr;
        if (r == k) {
#pragma unroll
          for (int e = 0; e < 4; ++e) vv[e] = rs[e];
          if (g == (k >> 2)) vv[k & 3] = pr;
        } else {
#pragma unroll
          for (int e = 0; e < 4; ++e) vv[e] = fmaf(-c, rs[e], vv[e]);
          if (g == (k >> 2)) vv[k & 3] = -c * pr;
        }
      }
      Pi[r * 20 + (g << 2) + 0] = vv[0];
      Pi[r * 20 + (g << 2) + 1] = vv[1];
      Pi[r * 20 + (g << 2) + 2] = vv[2];
      Pi[r * 20 + (g << 2) + 3] = vv[3];
    }
    __syncthreads();

    // ---- phase 2: Rp = Pinv @ A[p,:]; save Cp = A[:,p] ----
    {
      float Ak[16];
#pragma unroll
      for (int k = 0; k < 16; ++k) Ak[k] = a[(pb + k) * 132 + j];
      const unsigned jj = (unsigned)(j - pb);
      const int r0 = rr << 2;
#pragma unroll
      for (int q = 0; q < 4; ++q) {
        const int r = r0 + q;
        float acc = 0.f;
#pragma unroll
        for (int k = 0; k < 16; ++k) acc = fmaf(Pi[r * 20 + k], Ak[k], acc);
        Rp[r * 132 + j] = (jj < 16u) ? Pi[r * 20 + jj] : acc;
      }
      const int i = j;
      const int cb = rr << 2;
      float4 cA = *(const float4*)&a[i * 132 + pb + cb];
      *(float4*)&Cp[i * 20 + cb] = cA;
    }
    __syncthreads();

    // ---- phase 3: full update, 32 rows per thread-group ----
    {
      float Rk[16];
#pragma unroll
      for (int k = 0; k < 16; ++k) Rk[k] = Rp[k * 132 + j];
      const unsigned jj = (unsigned)(j - pb);
      const int i0 = rr << 5;
#pragma unroll 4
      for (int m = 0; m < 32; ++m) {
        const int i = i0 + m;
        const float4 c0 = *(const float4*)&Cp[i * 20];
        const float4 c1 = *(const float4*)&Cp[i * 20 + 4];
        const float4 c2 = *(const float4*)&Cp[i * 20 + 8];
        const float4 c3 = *(const float4*)&Cp[i * 20 + 12];
        float u0 = c0.x * Rk[0] + c0.y * Rk[1] + c0.z * Rk[2] + c0.w * Rk[3];
        float u1 = c1.x * Rk[4] + c1.y * Rk[5] + c1.z * Rk[6] + c1.w * Rk[7];
        float u2 = c2.x * Rk[8] + c2.y * Rk[9] + c2.z * Rk[10] + c2.w * Rk[11];
        float u3 = c3.x * Rk[12] + c3.y * Rk[13] + c3.z * Rk[14] + c3.w * Rk[15];
        const float upd = (u0 + u1) + (u2 + u3);
        const unsigned ii = (unsigned)(i - pb);
        float newv;
        if (ii < 16u) {
          newv = Rk[ii];
        } else {
          const float base = (jj < 16u) ? 0.f : a[i * 132 + j];
          newv = base - upd;
        }
        a[i * 132 + j] = newv;
      }
    }
    __syncthreads();
  }

  float* __restrict__ O = Sinv + (size_t)b * (K_ * K_);
#pragma unroll
  for (int l = 0; l < 8; ++l) {
    int f = t + (l << 9);
    int i = f >> 5, jq = (f & 31) << 2;
    *(float4*)(O + i * K_ + jq) = *(const float4*)&a[i * 132 + jq];
  }
}

// ---------------------------------------------------------------------------
// Kernel 6: Neumann iteration, 4 blocks per batch (32 rows each).
// Xout = (R - W .* Xin) @ Sinv ; W[i,k]=LMBDA*((q2i-q1k)^2+(p2i-p1k)^2)
// ---------------------------------------------------------------------------
__global__ __launch_bounds__(256)
void solve_iter(const float* __restrict__ Rm, const float* __restrict__ Sinv,
                const float* __restrict__ PQ, const float* __restrict__ Xin,
                float* __restrict__ Xout, const int first) {
  const int bb = blockIdx.x;
  const int b = bb >> 2, rb = (bb & 3) << 5;
  const int t = threadIdx.x;
  __shared__ float Tt[32][34];   // [kk][i_loc]; stride 34 -> conflict-light
  __shared__ float Sv[32][132];  // [kk][j]
  __shared__ float q1[K_], p1[K_], q2l[32], p2l[32];
  {
    const float* P = PQ + b * 512;
    if (t < K_) { q1[t] = P[t]; p1[t] = P[128 + t]; }
    if (t < 32) { q2l[t] = P[256 + rb + t]; p2l[t] = P[384 + rb + t]; }
  }
  __syncthreads();
  const float* __restrict__ Rb = Rm + (size_t)b * (K_ * K_);
  const float* __restrict__ Xb = Xin + (size_t)b * (K_ * K_);
  const float* __restrict__ Si = Sinv + (size_t)b * (K_ * K_);
  const int ir = (t >> 4) << 1, jc = (t & 15) << 3;
  float acc[2][8] = {};

  for (int k0 = 0; k0 < K_; k0 += 32) {
    {
      const int i = t >> 3;            // 0..31
      const int kk = (t & 7) << 2;
      const int k = k0 + kk;
      const int gi = rb + i;
      float4 tv = *(const float4*)(Rb + (size_t)gi * K_ + k);
      if (!first) {
        const float4 x4 = *(const float4*)(Xb + (size_t)gi * K_ + k);
        const float qi = q2l[i], pi = p2l[i];
        float dq, dp, w;
        dq = qi - q1[k + 0]; dp = pi - p1[k + 0]; w = fmaf(dq, dq, dp * dp);
        tv.x = fmaf(-LMBDA * w, x4.x, tv.x);
        dq = qi - q1[k + 1]; dp = pi - p1[k + 1]; w = fmaf(dq, dq, dp * dp);
        tv.y = fmaf(-LMBDA * w, x4.y, tv.y);
        dq = qi - q1[k + 2]; dp = pi - p1[k + 2]; w = fmaf(dq, dq, dp * dp);
        tv.z = fmaf(-LMBDA * w, x4.z, tv.z);
        dq = qi - q1[k + 3]; dp = pi - p1[k + 3]; w = fmaf(dq, dq, dp * dp);
        tv.w = fmaf(-LMBDA * w, x4.w, tv.w);
      }
      Tt[kk + 0][i] = tv.x; Tt[kk + 1][i] = tv.y;
      Tt[kk + 2][i] = tv.z; Tt[kk + 3][i] = tv.w;
    }
#pragma unroll
    for (int l = 0; l < 4; ++l) {
      int f = t + (l << 8);
      int kk = f >> 5, j4 = (f & 31) << 2;
      *(float4*)&Sv[kk][j4] = *(const float4*)(Si + (size_t)(k0 + kk) * K_ + j4);
    }
    __syncthreads();
#pragma unroll
    for (int kk = 0; kk < 32; ++kk) {
      const float2 a2 = *(const float2*)&Tt[kk][ir];
      const float4 b0 = *(const float4*)&Sv[kk][jc];
      const float4 b1 = *(const float4*)&Sv[kk][jc + 4];
      const float bv[8] = {b0.x, b0.y, b0.z, b0.w, b1.x, b1.y, b1.z, b1.w};
#pragma unroll
      for (int jx = 0; jx < 8; ++jx) {
        acc[0][jx] = fmaf(a2.x, bv[jx], acc[0][jx]);
        acc[1][jx] = fmaf(a2.y, bv[jx], acc[1][jx]);
      }
    }
    __syncthreads();
  }

  float* __restrict__ O = Xout + (size_t)b * (K_ * K_);
#pragma unroll
  for (int i = 0; i < 2; ++i) {
    float4 o0 = {acc[i][0], acc[i][1], acc[i][2], acc[i][3]};
    float4 o1 = {acc[i][4], acc[i][5], acc[i][6], acc[i][7]};
    *(float4*)(O + (size_t)(rb + ir + i) * K_ + jc) = o0;
    *(float4*)(O + (size_t)(rb + ir + i) * K_ + jc + 4) = o1;
  }
}

// ---------------------------------------------------------------------------
extern "C" void kernel_launch(void* const* d_in, const int* in_sizes, int n_in,
                              void* d_out, int out_size, void* d_ws, size_t ws_size,
                              hipStream_t stream) {
  (void)in_sizes; (void)n_in; (void)out_size;
  const float* feat_x  = (const float*)d_in[0];
  const float* feat_y  = (const float*)d_in[1];
  const float* evals_x = (const float*)d_in[2];
  const float* evals_y = (const float*)d_in[3];
  const float* evtx    = (const float*)d_in[4];
  const float* evty    = (const float*)d_in[5];
  float* out = (float*)d_out;
  float* ws  = (float*)d_ws;

  const size_t KC16 = (size_t)16 * K_ * C_;  // 524288 floats
  const size_t KK   = (size_t)K_ * K_;       // 16384
  const size_t fixed = KC16 + 3 * (KK * B_) + 4096 + 2 * (KK * B_);
  const int T = N_ / 32;  // 625 k-steps total

  int S = 16, Sa = 16, chunk = 0;
  for (;;) {
    int steps = (T + S - 1) / S;
    chunk = steps * 32;
    Sa = (T + steps - 1) / steps;  // active slabs, all with nb < N_
    if (((size_t)Sa * KC16 + fixed) * sizeof(float) <= ws_size || S == 1) break;
    S >>= 1;
  }

  float* part = ws;
  float* AB   = part + (size_t)Sa * KC16;
  float* Sm   = AB + KC16;
  float* Rm   = Sm + KK * B_;
  float* Sinv = Rm + KK * B_;
  float* PQ   = Sinv + KK * B_;
  float* X0   = PQ + 4096;
  float* X1   = X0 + KK * B_;

  mask_prep<<<dim3(8), 128, 0, stream>>>(evals_x, evals_y, PQ);
  proj_mfma<<<dim3(2, Sa, 16), 512, 0, stream>>>(feat_x, feat_y, evtx, evty, part, Sa, chunk);
  reduce_parts<<<dim3(16 * K_ * C_ / 4 / 256), 256, 0, stream>>>(part, AB, Sa);
  gram_kernel<<<dim3(8, 2, 4), 256, 0, stream>>>(AB, Sm, Rm);
  gj_inverse<<<dim3(8), 512, 0, stream>>>(Sm, Sinv);
  solve_iter<<<dim3(32), 256, 0, stream>>>(Rm, Sinv, PQ, X0, X0, 1);
  solve_iter<<<dim3(32), 256, 0, stream>>>(Rm, Sinv, PQ, X0, X1, 0);
  solve_iter<<<dim3(32), 256, 0, stream>>>(Rm, Sinv, PQ, X1, out, 0);
}

// Round 6
// 254.189 us; speedup vs baseline: 4.8182x; 1.0090x over previous
//
#include <hip/hip_runtime.h>
#include <math.h>

#define B_ 8
#define N_ 20000
#define K_ 128
#define C_ 256

static_assert(N_ % 32 == 0, "N must be multiple of 32");

constexpr float LMBDA = 100.0f;
constexpr float EPS_EV = 1e-10f;

typedef unsigned int u32x4 __attribute__((ext_vector_type(4)));
typedef short short8_t __attribute__((ext_vector_type(8)));
typedef float f32x4 __attribute__((ext_vector_type(4)));

// Split two fp32 into bf16 hi-plane (truncation; residual exact) and
// bf16 lo-plane (RNE of residual). Packed as (x1|x0) u32 words.
static __device__ inline void split2(float x0, float x1, unsigned& h, unsigned& l) {
  unsigned u0 = __builtin_bit_cast(unsigned, x0);
  unsigned u1 = __builtin_bit_cast(unsigned, x1);
  h = __builtin_amdgcn_perm(u1, u0, 0x07060302u);  // top16(x1)<<16 | top16(x0)
  float r0 = x0 - __builtin_bit_cast(float, u0 & 0xFFFF0000u);  // exact
  float r1 = x1 - __builtin_bit_cast(float, u1 & 0xFFFF0000u);  // exact
  unsigned v0 = __builtin_bit_cast(unsigned, r0);
  unsigned v1 = __builtin_bit_cast(unsigned, r1);
  v0 += 0x7FFFu + ((v0 >> 16) & 1u);  // RNE to bf16
  v1 += 0x7FFFu + ((v1 >> 16) & 1u);
  l = __builtin_amdgcn_perm(v1, v0, 0x07060302u);
}

// publish LDS writes + retire LDS reads, then raw barrier (no vmcnt drain --
// this is the whole point: global prefetch loads stay in flight across it).
#define KFENCE()                                              \
  do {                                                        \
    asm volatile("s_waitcnt lgkmcnt(0)" ::: "memory");        \
    __builtin_amdgcn_sched_barrier(0);                        \
    __builtin_amdgcn_s_barrier();                             \
    __builtin_amdgcn_sched_barrier(0);                        \
  } while (0)

// ---------------------------------------------------------------------------
// Kernel 1: projection GEMM, bf16x3 split MFMA.
// Double-buffered LDS, ONE raw barrier per K-step, loads in flight across
// barriers (reg-staged T14 + T3/T4 counted-wait structure).
// B-plane slot swizzle kills the 8-way write conflicts of the 80B stride.
// ---------------------------------------------------------------------------
__global__ __launch_bounds__(512, 4)
void proj_mfma(const float* __restrict__ feat_x, const float* __restrict__ feat_y,
               const float* __restrict__ evx, const float* __restrict__ evy,
               float* __restrict__ part, int Sa, int chunk) {
  const int bm = blockIdx.z;
  const int b = bm >> 1, mat = bm & 1;
  const float* __restrict__ E = (mat ? evy : evx) + (size_t)b * K_ * N_;
  const float* __restrict__ F = (mat ? feat_y : feat_x) + (size_t)b * N_ * C_;
  const int c0 = blockIdx.x << 7;
  const int s = blockIdx.y;
  const int nb = s * chunk;
  const int ne = min(N_, nb + chunk);
  const int nt = (ne - nb) >> 5;

  __shared__ unsigned short Ah[2][128][40];
  __shared__ unsigned short Al[2][128][40];
  __shared__ unsigned short Bh[2][128][40];
  __shared__ unsigned short Bl[2][128][40];

  const int t = threadIdx.x;
  const int lane = t & 63, wv = t >> 6;
  const int wm = wv & 3;          // m-tile 0..3 (32 rows each)
  const int wcc = wv >> 2;        // c-tile 0..1 (64 cols each)
  const int lr = lane & 15, lg = lane >> 4;

  // staging maps
  const int am = t >> 2, ak = (t & 3) << 3;      // A: row am, k ak..ak+7
  const int cl = t & 127, gq = (t >> 7) << 2;    // B: col cl, n quads gq, gq+16
  const int sigw = ((cl >> 3) & 3) << 1;         // B write slot swizzle
  const int slotA = ((gq >> 2) ^ sigw) << 2;     // element offsets
  const int slotB = (((gq >> 2) + 4) ^ sigw) << 2;

  f32x4 acc[2][4];
#pragma unroll
  for (int i = 0; i < 2; ++i)
#pragma unroll
    for (int j = 0; j < 4; ++j) acc[i][j] = (f32x4){0.f, 0.f, 0.f, 0.f};

  struct Stage { float4 a0, a1; float b0, b1, b2, b3, b4, b5, b6, b7; };

  auto LOAD = [&](Stage& st, int n0) {
    const float* ep = E + (size_t)am * N_ + n0 + ak;
    st.a0 = *(const float4*)ep;
    st.a1 = *(const float4*)(ep + 4);
    const float* fp = F + (size_t)(n0 + gq) * C_ + c0 + cl;
    st.b0 = fp[0];
    st.b1 = fp[C_];
    st.b2 = fp[2 * C_];
    st.b3 = fp[3 * C_];
    const float* fp2 = fp + (size_t)16 * C_;
    st.b4 = fp2[0];
    st.b5 = fp2[C_];
    st.b6 = fp2[2 * C_];
    st.b7 = fp2[3 * C_];
  };

  auto WRITE = [&](Stage& st, int p) {
    unsigned h01, l01, h23, l23, h45, l45, h67, l67;
    split2(st.a0.x, st.a0.y, h01, l01);
    split2(st.a0.z, st.a0.w, h23, l23);
    split2(st.a1.x, st.a1.y, h45, l45);
    split2(st.a1.z, st.a1.w, h67, l67);
    *(u32x4*)&Ah[p][am][ak] = (u32x4){h01, h23, h45, h67};
    *(u32x4*)&Al[p][am][ak] = (u32x4){l01, l23, l45, l67};
    split2(st.b0, st.b1, h01, l01);
    split2(st.b2, st.b3, h23, l23);
    *(uint2*)&Bh[p][cl][slotA] = (uint2){h01, h23};
    *(uint2*)&Bl[p][cl][slotA] = (uint2){l01, l23};
    split2(st.b4, st.b5, h45, l45);
    split2(st.b6, st.b7, h67, l67);
    *(uint2*)&Bh[p][cl][slotB] = (uint2){h45, h67};
    *(uint2*)&Bl[p][cl][slotB] = (uint2){l45, l67};
  };

  auto COMPUTE = [&](int p) {
    const int k0 = lg << 3;
    short8_t a_h[2], a_l[2];
#pragma unroll
    for (int mt = 0; mt < 2; ++mt) {
      const int m = (wm << 5) + (mt << 4) + lr;
      a_h[mt] = *(const short8_t*)&Ah[p][m][k0];
      a_l[mt] = *(const short8_t*)&Al[p][m][k0];
    }
#pragma unroll
    for (int ct = 0; ct < 4; ++ct) {
      const int c = (wcc << 6) + (ct << 4) + lr;
      const int sig = ((c >> 3) & 3) << 1;
      const int koff = (((lg << 1) ^ sig)) << 2;
      const short8_t b_h = *(const short8_t*)&Bh[p][c][koff];
      const short8_t b_l = *(const short8_t*)&Bl[p][c][koff];
#pragma unroll
      for (int mt = 0; mt < 2; ++mt) {
        acc[mt][ct] = __builtin_amdgcn_mfma_f32_16x16x32_bf16(a_h[mt], b_h, acc[mt][ct], 0, 0, 0);
        acc[mt][ct] = __builtin_amdgcn_mfma_f32_16x16x32_bf16(a_l[mt], b_h, acc[mt][ct], 0, 0, 0);
        acc[mt][ct] = __builtin_amdgcn_mfma_f32_16x16x32_bf16(a_h[mt], b_l, acc[mt][ct], 0, 0, 0);
      }
    }
  };

  Stage sA, sB;
  LOAD(sA, nb);                       // tile 0
  if (nt > 1) LOAD(sB, nb + 32);      // tile 1
  WRITE(sA, 0);                       // waits only tile-0 loads
  KFENCE();

  for (int it = 0; it < nt; it += 2) {
    // even step: compute buf0 (tile it); publish tile it+1 into buf1
    if (it + 1 < nt) WRITE(sB, 1);                    // vmcnt wait: tile it+1 (issued 1 iter ago)
    if (it + 2 < nt) LOAD(sA, nb + ((it + 2) << 5));  // issued AFTER the wait -> never drained
    COMPUTE(0);
    KFENCE();
    if (it + 1 < nt) {
      // odd step: compute buf1 (tile it+1); publish tile it+2 into buf0
      if (it + 2 < nt) WRITE(sA, 0);
      if (it + 3 < nt) LOAD(sB, nb + ((it + 3) << 5));
      COMPUTE(1);
      KFENCE();
    }
  }

  // epilogue: C/D layout col=lane&15, row=(lane>>4)*4+r
  float* __restrict__ P = part + ((size_t)bm * Sa + s) * (K_ * C_);
#pragma unroll
  for (int mt = 0; mt < 2; ++mt)
#pragma unroll
    for (int ct = 0; ct < 4; ++ct) {
      const int ccol = c0 + (wcc << 6) + (ct << 4) + lr;
#pragma unroll
      for (int r = 0; r < 4; ++r) {
        const int mrow = (wm << 5) + (mt << 4) + (lg << 2) + r;
        P[(size_t)mrow * C_ + ccol] = acc[mt][ct][r];
      }
    }
}

// ---------------------------------------------------------------------------
// Kernel 2: reduce split-n partials -> AB (float4 vectorized)
// ---------------------------------------------------------------------------
__global__ void reduce_parts(const float* __restrict__ part, float* __restrict__ AB, int Sa) {
  const int idx4 = blockIdx.x * 256 + threadIdx.x;       // float4 units
  if (idx4 >= 16 * K_ * C_ / 4) return;
  const int per = K_ * C_ / 4;
  const int bm = idx4 / per;
  const int rem4 = idx4 - bm * per;
  float4 v = {0.f, 0.f, 0.f, 0.f};
  for (int s = 0; s < Sa; ++s) {
    const float4 p = *(const float4*)&part[((size_t)bm * Sa + s) * (K_ * C_) + rem4 * 4];
    v.x += p.x; v.y += p.y; v.z += p.z; v.w += p.w;
  }
  *(float4*)&AB[(size_t)idx4 * 4] = v;
}

// ---------------------------------------------------------------------------
// Kernel 3: gram matrices, 64x64 quadrant per block (8 x 2 x 4 grid).
// which=0: Sm = A A^T + 1e-8 I ; which=1: Rm = Bm A^T
// ---------------------------------------------------------------------------
__global__ __launch_bounds__(256)
void gram_kernel(const float* __restrict__ AB, float* __restrict__ Sm, float* __restrict__ Rm) {
  const int b = blockIdx.x, which = blockIdx.y, qz = blockIdx.z;
  const int iq = (qz & 1) << 6, jq = (qz >> 1) << 6;
  const float* __restrict__ L  = AB + ((size_t)(b * 2 + which)) * (K_ * C_);
  const float* __restrict__ Ar = AB + ((size_t)(b * 2)) * (K_ * C_);
  float* __restrict__ out = (which ? Rm : Sm) + (size_t)b * (K_ * K_);
  const int t = threadIdx.x;
  const int ir = iq + ((t >> 4) << 2), jc = jq + ((t & 15) << 2);
  float acc[4][4] = {};
  for (int c0 = 0; c0 < C_; c0 += 4) {
    float4 li[4], rj[4];
#pragma unroll
    for (int i = 0; i < 4; ++i) li[i] = *(const float4*)(L + (size_t)(ir + i) * C_ + c0);
#pragma unroll
    for (int j = 0; j < 4; ++j) rj[j] = *(const float4*)(Ar + (size_t)(jc + j) * C_ + c0);
#pragma unroll
    for (int i = 0; i < 4; ++i)
#pragma unroll
      for (int j = 0; j < 4; ++j)
        acc[i][j] += li[i].x * rj[j].x + li[i].y * rj[j].y +
                     li[i].z * rj[j].z + li[i].w * rj[j].w;
  }
#pragma unroll
  for (int i = 0; i < 4; ++i)
#pragma unroll
    for (int j = 0; j < 4; ++j) {
      float v = acc[i][j];
      if (!which && (ir + i) == (jc + j)) v += 1e-8f;
      out[(size_t)(ir + i) * K_ + (jc + j)] = v;
    }
}

// ---------------------------------------------------------------------------
// Kernel 4: mask prep -> q1,p1 (cols, evals_x), q2,p2 (rows, evals_y)
// ---------------------------------------------------------------------------
__global__ void mask_prep(const float* __restrict__ evx, const float* __restrict__ evy,
                          float* __restrict__ PQ) {
  const int b = blockIdx.x, t = threadIdx.x;  // 128 threads
  float e1 = evx[b * K_ + t];
  float e2 = evy[b * K_ + t];
  if (e1 != e1) e1 = EPS_EV;
  if (e2 != e2) e2 = EPS_EV;
  e1 = fminf(fmaxf(e1, EPS_EV), 1e6f);
  e2 = fminf(fmaxf(e2, EPS_EV), 1e6f);

  __shared__ float wmax[2];
  float v = fmaxf(e1, e2);
#pragma unroll
  for (int d = 1; d < 64; d <<= 1) v = fmaxf(v, __shfl_xor(v, d, 64));
  if ((t & 63) == 0) wmax[t >> 6] = v;
  __syncthreads();
  const float scale = fmaxf(fmaxf(wmax[0], wmax[1]), 1e-10f);

  const float g1 = sqrtf(e1 / scale);
  const float g2 = sqrtf(e2 / scale);
  const float d1 = fmaf(g1, g1, 1.f);
  const float d2 = fmaf(g2, g2, 1.f);
  float* P = PQ + b * 512;
  P[t]       = g1 / d1;
  P[128 + t] = 1.f / d1;
  P[256 + t] = g2 / d2;
  P[384 + t] = 1.f / d2;
}

// ---------------------------------------------------------------------------
// Kernel 5: BLOCKED Gauss-Jordan inverse (SPD), 16x16 pivot panels, 512 thr.
// ---------------------------------------------------------------------------
__global__ __launch_bounds__(512)
void gj_inverse(const float* __restrict__ Sm, float* __restrict__ Sinv) {
  const int b = blockIdx.x, t = threadIdx.x;
  __shared__ float a[K_ * 132];
  __shared__ float Pi[16 * 20];
  __shared__ float Rp[16 * 132];
  __shared__ float Cp[K_ * 20];
  const float* __restrict__ Sb = Sm + (size_t)b * (K_ * K_);
#pragma unroll
  for (int l = 0; l < 8; ++l) {
    int f = t + (l << 9);
    int i = f >> 5, j = (f & 31) << 2;
    *(float4*)&a[i * 132 + j] = *(const float4*)(Sb + i * K_ + j);
  }
  __syncthreads();

  const int j = t & 127, rr = t >> 7;   // rr in 0..3
  const int lane = t & 63;

  for (int p = 0; p < 8; ++p) {
    const int pb = p << 4;

    if (t < 64) {
      const int r = lane & 15, g = lane >> 4;
      float4 v4 = *(const float4*)&a[(pb + r) * 132 + pb + (g << 2)];
      float vv[4] = {v4.x, v4.y, v4.z, v4.w};
#pragma unroll
      for (int k = 0; k < 16; ++k) {
        const int srcrow = (lane & 48) | k;
        float rk[4];
        rk[0] = __shfl(vv[0], srcrow);
        rk[1] = __shfl(vv[1], srcrow);
        rk[2] = __shfl(vv[2], srcrow);
        rk[3] = __shfl(vv[3], srcrow);
        const int kg = (k >> 2) << 4;
        const float pv = __shfl(vv[k & 3], kg | k);
        const float c  = __shfl(vv[k & 3], kg | r);
        const float pr = 1.0f / pv;
        float rs[4];
#pragma unroll
        for (int e = 0; e < 4; ++e) rs[e] = rk[e] * pr;
        if (r == k) {
#pragma unroll
          for (int e = 0; e < 4; ++e) vv[e] = rs[e];
          if (g == (k >> 2)) vv[k & 3] = pr;
        } else {
#pragma unroll
          for (int e = 0; e < 4; ++e) vv[e] = fmaf(-c, rs[e], vv[e]);
          if (g == (k >> 2)) vv[k & 3] = -c * pr;
        }
      }
      Pi[r * 20 + (g << 2) + 0] = vv[0];
      Pi[r * 20 + (g << 2) + 1] = vv[1];
      Pi[r * 20 + (g << 2) + 2] = vv[2];
      Pi[r * 20 + (g << 2) + 3] = vv[3];
    }
    __syncthreads();

    {
      float Ak[16];
#pragma unroll
      for (int k = 0; k < 16; ++k) Ak[k] = a[(pb + k) * 132 + j];
      const unsigned jj = (unsigned)(j - pb);
      const int r0 = rr << 2;
#pragma unroll
      for (int q = 0; q < 4; ++q) {
        const int r = r0 + q;
        float acc = 0.f;
#pragma unroll
        for (int k = 0; k < 16; ++k) acc = fmaf(Pi[r * 20 + k], Ak[k], acc);
        Rp[r * 132 + j] = (jj < 16u) ? Pi[r * 20 + jj] : acc;
      }
      const int i = j;
      const int cb = rr << 2;
      float4 cA = *(const float4*)&a[i * 132 + pb + cb];
      *(float4*)&Cp[i * 20 + cb] = cA;
    }
    __syncthreads();

    {
      float Rk[16];
#pragma unroll
      for (int k = 0; k < 16; ++k) Rk[k] = Rp[k * 132 + j];
      const unsigned jj = (unsigned)(j - pb);
      const int i0 = rr << 5;
#pragma unroll 4
      for (int m = 0; m < 32; ++m) {
        const int i = i0 + m;
        const float4 c0 = *(const float4*)&Cp[i * 20];
        const float4 c1 = *(const float4*)&Cp[i * 20 + 4];
        const float4 c2 = *(const float4*)&Cp[i * 20 + 8];
        const float4 c3 = *(const float4*)&Cp[i * 20 + 12];
        float u0 = c0.x * Rk[0] + c0.y * Rk[1] + c0.z * Rk[2] + c0.w * Rk[3];
        float u1 = c1.x * Rk[4] + c1.y * Rk[5] + c1.z * Rk[6] + c1.w * Rk[7];
        float u2 = c2.x * Rk[8] + c2.y * Rk[9] + c2.z * Rk[10] + c2.w * Rk[11];
        float u3 = c3.x * Rk[12] + c3.y * Rk[13] + c3.z * Rk[14] + c3.w * Rk[15];
        const float upd = (u0 + u1) + (u2 + u3);
        const unsigned ii = (unsigned)(i - pb);
        float newv;
        if (ii < 16u) {
          newv = Rk[ii];
        } else {
          const float base = (jj < 16u) ? 0.f : a[i * 132 + j];
          newv = base - upd;
        }
        a[i * 132 + j] = newv;
      }
    }
    __syncthreads();
  }

  float* __restrict__ O = Sinv + (size_t)b * (K_ * K_);
#pragma unroll
  for (int l = 0; l < 8; ++l) {
    int f = t + (l << 9);
    int i = f >> 5, jq = (f & 31) << 2;
    *(float4*)(O + i * K_ + jq) = *(const float4*)&a[i * 132 + jq];
  }
}

// ---------------------------------------------------------------------------
// Kernel 6: Neumann iteration, 4 blocks per batch (32 rows each).
// Xout = (R - W .* Xin) @ Sinv ; W[i,k]=LMBDA*((q2i-q1k)^2+(p2i-p1k)^2)
// ---------------------------------------------------------------------------
__global__ __launch_bounds__(256)
void solve_iter(const float* __restrict__ Rm, const float* __restrict__ Sinv,
                const float* __restrict__ PQ, const float* __restrict__ Xin,
                float* __restrict__ Xout, const int first) {
  const int bb = blockIdx.x;
  const int b = bb >> 2, rb = (bb & 3) << 5;
  const int t = threadIdx.x;
  __shared__ float Tt[32][34];
  __shared__ float Sv[32][132];
  __shared__ float q1[K_], p1[K_], q2l[32], p2l[32];
  {
    const float* P = PQ + b * 512;
    if (t < K_) { q1[t] = P[t]; p1[t] = P[128 + t]; }
    if (t < 32) { q2l[t] = P[256 + rb + t]; p2l[t] = P[384 + rb + t]; }
  }
  __syncthreads();
  const float* __restrict__ Rb = Rm + (size_t)b * (K_ * K_);
  const float* __restrict__ Xb = Xin + (size_t)b * (K_ * K_);
  const float* __restrict__ Si = Sinv + (size_t)b * (K_ * K_);
  const int ir = (t >> 4) << 1, jc = (t & 15) << 3;
  float acc[2][8] = {};

  for (int k0 = 0; k0 < K_; k0 += 32) {
    {
      const int i = t >> 3;            // 0..31
      const int kk = (t & 7) << 2;
      const int k = k0 + kk;
      const int gi = rb + i;
      float4 tv = *(const float4*)(Rb + (size_t)gi * K_ + k);
      if (!first) {
        const float4 x4 = *(const float4*)(Xb + (size_t)gi * K_ + k);
        const float qi = q2l[i], pi = p2l[i];
        float dq, dp, w;
        dq = qi - q1[k + 0]; dp = pi - p1[k + 0]; w = fmaf(dq, dq, dp * dp);
        tv.x = fmaf(-LMBDA * w, x4.x, tv.x);
        dq = qi - q1[k + 1]; dp = pi - p1[k + 1]; w = fmaf(dq, dq, dp * dp);
        tv.y = fmaf(-LMBDA * w, x4.y, tv.y);
        dq = qi - q1[k + 2]; dp = pi - p1[k + 2]; w = fmaf(dq, dq, dp * dp);
        tv.z = fmaf(-LMBDA * w, x4.z, tv.z);
        dq = qi - q1[k + 3]; dp = pi - p1[k + 3]; w = fmaf(dq, dq, dp * dp);
        tv.w = fmaf(-LMBDA * w, x4.w, tv.w);
      }
      Tt[kk + 0][i] = tv.x; Tt[kk + 1][i] = tv.y;
      Tt[kk + 2][i] = tv.z; Tt[kk + 3][i] = tv.w;
    }
#pragma unroll
    for (int l = 0; l < 4; ++l) {
      int f = t + (l << 8);
      int kk = f >> 5, j4 = (f & 31) << 2;
      *(float4*)&Sv[kk][j4] = *(const float4*)(Si + (size_t)(k0 + kk) * K_ + j4);
    }
    __syncthreads();
#pragma unroll
    for (int kk = 0; kk < 32; ++kk) {
      const float2 a2 = *(const float2*)&Tt[kk][ir];
      const float4 b0 = *(const float4*)&Sv[kk][jc];
      const float4 b1 = *(const float4*)&Sv[kk][jc + 4];
      const float bv[8] = {b0.x, b0.y, b0.z, b0.w, b1.x, b1.y, b1.z, b1.w};
#pragma unroll
      for (int jx = 0; jx < 8; ++jx) {
        acc[0][jx] = fmaf(a2.x, bv[jx], acc[0][jx]);
        acc[1][jx] = fmaf(a2.y, bv[jx], acc[1][jx]);
      }
    }
    __syncthreads();
  }

  float* __restrict__ O = Xout + (size_t)b * (K_ * K_);
#pragma unroll
  for (int i = 0; i < 2; ++i) {
    float4 o0 = {acc[i][0], acc[i][1], acc[i][2], acc[i][3]};
    float4 o1 = {acc[i][4], acc[i][5], acc[i][6], acc[i][7]};
    *(float4*)(O + (size_t)(rb + ir + i) * K_ + jc) = o0;
    *(float4*)(O + (size_t)(rb + ir + i) * K_ + jc + 4) = o1;
  }
}

// ---------------------------------------------------------------------------
extern "C" void kernel_launch(void* const* d_in, const int* in_sizes, int n_in,
                              void* d_out, int out_size, void* d_ws, size_t ws_size,
                              hipStream_t stream) {
  (void)in_sizes; (void)n_in; (void)out_size;
  const float* feat_x  = (const float*)d_in[0];
  const float* feat_y  = (const float*)d_in[1];
  const float* evals_x = (const float*)d_in[2];
  const float* evals_y = (const float*)d_in[3];
  const float* evtx    = (const float*)d_in[4];
  const float* evty    = (const float*)d_in[5];
  float* out = (float*)d_out;
  float* ws  = (float*)d_ws;

  const size_t KC16 = (size_t)16 * K_ * C_;  // 524288 floats
  const size_t KK   = (size_t)K_ * K_;       // 16384
  const size_t fixed = KC16 + 3 * (KK * B_) + 4096 + 2 * (KK * B_);
  const int T = N_ / 32;  // 625 k-steps total

  int S = 16, Sa = 16, chunk = 0;
  for (;;) {
    int steps = (T + S - 1) / S;
    chunk = steps * 32;
    Sa = (T + steps - 1) / steps;  // active slabs, all with nb < N_
    if (((size_t)Sa * KC16 + fixed) * sizeof(float) <= ws_size || S == 1) break;
    S >>= 1;
  }

  float* part = ws;
  float* AB   = part + (size_t)Sa * KC16;
  float* Sm   = AB + KC16;
  float* Rm   = Sm + KK * B_;
  float* Sinv = Rm + KK * B_;
  float* PQ   = Sinv + KK * B_;
  float* X0   = PQ + 4096;
  float* X1   = X0 + KK * B_;

  mask_prep<<<dim3(8), 128, 0, stream>>>(evals_x, evals_y, PQ);
  proj_mfma<<<dim3(2, Sa, 16), 512, 0, stream>>>(feat_x, feat_y, evtx, evty, part, Sa, chunk);
  reduce_parts<<<dim3(16 * K_ * C_ / 4 / 256), 256, 0, stream>>>(part, AB, Sa);
  gram_kernel<<<dim3(8, 2, 4), 256, 0, stream>>>(AB, Sm, Rm);
  gj_inverse<<<dim3(8), 512, 0, stream>>>(Sm, Sinv);
  solve_iter<<<dim3(32), 256, 0, stream>>>(Rm, Sinv, PQ, X0, X0, 1);
  solve_iter<<<dim3(32), 256, 0, stream>>>(Rm, Sinv, PQ, X0, X1, 0);
  solve_iter<<<dim3(32), 256, 0, stream>>>(Rm, Sinv, PQ, X1, out, 0);
}